// Round 8
// baseline (351.167 us; speedup 1.0000x reference)
//
#include <hip/hip_runtime.h>
#include <math.h>

// Problem constants (from setup_inputs): B,V,C,D,H,W = 2,5,32,48,128,160
constexpr int B_ = 2;
constexpr int V_ = 5;
constexpr int C_ = 32;
constexpr int D_ = 48;
constexpr int H_ = 128;
constexpr int W_ = 160;
constexpr int HW_ = H_ * W_;               // 20480
constexpr int NVOX = B_ * D_ * HW_;        // 1,966,080
constexpr int PLANE = D_ * HW_;            // 983,040 (per-batch voxels)

typedef _Float16 half2_t __attribute__((ext_vector_type(2)));
typedef _Float16 half8_t __attribute__((ext_vector_type(8)));
typedef float floatx4 __attribute__((ext_vector_type(4)));

// ---------------- small matrix helpers (device) ----------------

__device__ inline void combine4(const float* pm, float out[4][4]) {
    const float* E = pm;
    const float* K = pm + 16;
    for (int i = 0; i < 3; ++i)
        for (int j = 0; j < 4; ++j) {
            float a = 0.f;
            for (int k = 0; k < 3; ++k) a += K[i * 4 + k] * E[k * 4 + j];
            out[i][j] = a;
        }
    for (int j = 0; j < 4; ++j) out[3][j] = E[12 + j];
}

__device__ inline void invert4(const float A[4][4], float inv[4][4]) {
    float M[4][8];
    for (int i = 0; i < 4; ++i)
        for (int j = 0; j < 4; ++j) {
            M[i][j] = A[i][j];
            M[i][4 + j] = (i == j) ? 1.f : 0.f;
        }
    for (int col = 0; col < 4; ++col) {
        int piv = col;
        float best = fabsf(M[col][col]);
        for (int r = col + 1; r < 4; ++r) {
            float v = fabsf(M[r][col]);
            if (v > best) { best = v; piv = r; }
        }
        if (piv != col)
            for (int j = 0; j < 8; ++j) { float t = M[col][j]; M[col][j] = M[piv][j]; M[piv][j] = t; }
        float ip = 1.f / M[col][col];
        for (int j = 0; j < 8; ++j) M[col][j] *= ip;
        for (int r = 0; r < 4; ++r) {
            if (r == col) continue;
            float f = M[r][col];
            for (int j = 0; j < 8; ++j) M[r][j] -= f * M[col][j];
        }
    }
    for (int i = 0; i < 4; ++i)
        for (int j = 0; j < 4; ++j) inv[i][j] = M[i][4 + j];
}

__device__ inline unsigned bf_rne(float f) {
    unsigned u = __float_as_uint(f);
    return (u + 0x7FFFu + ((u >> 16) & 1u)) >> 16;   // RNE (values are finite)
}

__device__ inline float bflo(unsigned u) { return __uint_as_float(u << 16); }
__device__ inline float bfhi(unsigned u) { return __uint_as_float(u & 0xffff0000u); }

__device__ inline unsigned h2pack(float a, float b) {   // fp16 RNE pair
    unsigned lo = (unsigned)__builtin_bit_cast(unsigned short, (_Float16)a);
    unsigned hi = (unsigned)__builtin_bit_cast(unsigned short, (_Float16)b);
    return lo | (hi << 16);
}

// pack two f32 -> two bf16 in one VALU op (RNE). No builtin on gfx950.
__device__ inline unsigned cvt_pk_bf16(float a, float b) {
    unsigned r;
    asm("v_cvt_pk_bf16_f32 %0, %1, %2" : "=v"(r) : "v"(a), "v"(b));
    return r;
}

// setup: (a) per b,v: P = src_proj @ inv(ref_proj) -> rt[12 floats]
//        (b) prepack conv weights as fp16 MFMA A-fragments:
//            A[m=tap=lane&15 (+16i)][k=ch=(lane>>4)*8+j], taps>=27 zero-padded
__global__ void setup_kernel(const float* __restrict__ proj, const float* __restrict__ wreg,
                             float* __restrict__ rt, unsigned* __restrict__ wtb) {
    int t = threadIdx.x;
    if (t < B_) {
        int b = t;
        float ref[4][4], inv[4][4];
        combine4(proj + (size_t)((b * V_ + 0) * 2) * 16, ref);
        invert4(ref, inv);
        for (int v = 1; v < V_; ++v) {
            float src[4][4];
            combine4(proj + (size_t)((b * V_ + v) * 2) * 16, src);
            float P[3][4];
            for (int i = 0; i < 3; ++i)
                for (int j = 0; j < 4; ++j) {
                    float a = 0.f;
                    for (int k = 0; k < 4; ++k) a += src[i][k] * inv[k][j];
                    P[i][j] = a;
                }
            float* o = rt + (size_t)(b * (V_ - 1) + (v - 1)) * 12;
            o[0] = P[0][0]; o[1] = P[0][1]; o[2] = P[0][2];
            o[3] = P[1][0]; o[4] = P[1][1]; o[5] = P[1][2];
            o[6] = P[2][0]; o[7] = P[2][1]; o[8] = P[2][2];
            o[9] = P[0][3]; o[10] = P[1][3]; o[11] = P[2][3];
        }
    }
    if (t < 128) {
        int i = t >> 6;          // which mfma (taps 0-15 / 16-31)
        int lane = t & 63;
        int q = lane >> 4;
        int l = lane & 15;
        int tap = i * 16 + l;
        unsigned u[4];
#pragma unroll
        for (int jj = 0; jj < 4; ++jj) {
            int ch0 = q * 8 + 2 * jj;
            float v0 = (tap < 27) ? wreg[ch0 * 27 + tap] : 0.f;
            float v1 = (tap < 27) ? wreg[(ch0 + 1) * 27 + tap] : 0.f;
            u[jj] = h2pack(v0, v1);
        }
        uint4* o = (uint4*)wtb;
        o[i * 64 + lane] = make_uint4(u[0], u[1], u[2], u[3]);
    }
}

// transpose features (B,V,C,H,W) f32 -> channel-last fp16 (B,V,H,W,C): 64 B/pixel
__global__ __launch_bounds__(256) void transpose_kernel(const float* __restrict__ feat,
                                                        unsigned* __restrict__ feat_cl) {
    int idx = blockIdx.x * 256 + threadIdx.x;  // over B*V*HW
    if (idx >= B_ * V_ * HW_) return;
    int pix = idx % HW_;
    int bv = idx / HW_;
    const float* src = feat + (size_t)bv * C_ * HW_ + pix;
    unsigned u[16];
#pragma unroll
    for (int j = 0; j < 16; ++j)
        u[j] = h2pack(src[(size_t)(2 * j) * HW_], src[(size_t)(2 * j + 1) * HW_]);
    uint4* dst = (uint4*)(feat_cl + (size_t)idx * 16);
    dst[0] = make_uint4(u[0], u[1], u[2], u[3]);
    dst[1] = make_uint4(u[4], u[5], u[6], u[7]);
    dst[2] = make_uint4(u[8], u[9], u[10], u[11]);
    dst[3] = make_uint4(u[12], u[13], u[14], u[15]);
}

// Fused homography warp + bilinear + variance + conv channel-reduction.
// Block = 256 threads = 64 pixels x 4 lanes; grid (320, D, B).
// v8 structure: lane j = tid&3 computes ONE view's projection (view j),
// gathers view j's 4 corners for ALL 4 channel quarters (quarter via
// compile-time +q*16 immediate offset), combines to per-view interp
// A[q][jj] in packed f16, then a 2-stage __shfl_xor butterfly transpose
// redistributes across the quad so each lane ends with its OWN quarter's
// interp from all 4 views (order lane-dependent; sum over views is
// order-insensitive). Squares taken per-view after exchange -> variance
// semantics unchanged. The shuffles sit AFTER the gathers (off the
// address critical path — r1's bottleneck), and projection VALU is 1x
// not 4x (r7's cost). No DPP, no launch_bounds forcing (r2-r6 lessons).
// T layout: [j=0..26][b][d][h][w], ushort (bf16).
__global__ __launch_bounds__(256) void warp_kernel(const unsigned char* __restrict__ fb,
                                                   const float* __restrict__ rt,
                                                   const float* __restrict__ dv,
                                                   const unsigned* __restrict__ wtb,
                                                   unsigned short* __restrict__ T) {
    const int tid = threadIdx.x;
    const int lane = tid & 63;
    const int j = tid & 3;                    // view index AND channel quarter
    const unsigned cq16 = (unsigned)j << 4;
    const int b = blockIdx.z;
    const int d = blockIdx.y;
    const int pixb = blockIdx.x * 64;         // block's first pixel
    const int pix = pixb + (tid >> 2);
    const int w = pix % W_;
    const int h = pix / W_;
    const float wf = (float)w, hf = (float)h;
    const float dep = dv[b * D_ + d];         // uniform -> s_load

    // A-fragments (fp16 conv weights), constant per lane
    const uint4* wp = (const uint4*)wtb;
    uint4 a0u = wp[lane];
    uint4 a1u = wp[64 + lane];

    // ref view: own pixel, own 8 channels; init packed f16 sum / sum-of-squares
    half2_t s2[4], q2[4];
    {
        const unsigned char* rb = fb + (size_t)(b * V_) * HW_ * 64;
        uint4 r = *(const uint4*)(rb + (((unsigned)pix) << 6) + cq16);
        unsigned ru[4] = {r.x, r.y, r.z, r.w};
#pragma unroll
        for (int jj = 0; jj < 4; ++jj) {
            half2_t f = __builtin_bit_cast(half2_t, ru[jj]);
            s2[jj] = f;
            q2[jj] = f * f;
        }
    }

    // own-view projection (view j) — r1-verified math verbatim
    unsigned W00u, W01u, W10u, W11u;          // half2 (w,w) per corner
    unsigned O00, O01, O10, O11;              // corner pixel byte offsets
    {
        const float* m = rt + (b * (V_ - 1) + j) * 12;
        float xp = fmaf(fmaf(m[0], wf, fmaf(m[1], hf, m[2])), dep, m[9]);
        float yp = fmaf(fmaf(m[3], wf, fmaf(m[4], hf, m[5])), dep, m[10]);
        float zp = fmaf(fmaf(m[6], wf, fmaf(m[7], hf, m[8])), dep, m[11]);
        float iz = __builtin_amdgcn_rcpf(zp);
        float ix = xp * iz, iy = yp * iz;
        float x0f = floorf(ix), y0f = floorf(iy);
        float wx1 = ix - x0f, wx0 = 1.f - wx1;
        float wy1 = iy - y0f, wy0 = 1.f - wy1;
        float x1f = x0f + 1.f, y1f = y0f + 1.f;
        float wx0v = (x0f >= 0.f && x0f <= (float)(W_ - 1)) ? wx0 : 0.f;
        float wx1v = (x1f >= 0.f && x1f <= (float)(W_ - 1)) ? wx1 : 0.f;
        float wy0v = (y0f >= 0.f && y0f <= (float)(H_ - 1)) ? wy0 : 0.f;
        float wy1v = (y1f >= 0.f && y1f <= (float)(H_ - 1)) ? wy1 : 0.f;
        int x0i = (int)fminf(fmaxf(x0f, 0.f), (float)(W_ - 1));
        int x1i = (int)fminf(fmaxf(x1f, 0.f), (float)(W_ - 1));
        int y0i = (int)fminf(fmaxf(y0f, 0.f), (float)(H_ - 1));
        int y1i = (int)fminf(fmaxf(y1f, 0.f), (float)(H_ - 1));
        float w00 = wx0v * wy0v, w01 = wx1v * wy0v;
        float w10 = wx0v * wy1v, w11 = wx1v * wy1v;
        W00u = __builtin_bit_cast(unsigned, __builtin_amdgcn_cvt_pkrtz(w00, w00));
        W01u = __builtin_bit_cast(unsigned, __builtin_amdgcn_cvt_pkrtz(w01, w01));
        W10u = __builtin_bit_cast(unsigned, __builtin_amdgcn_cvt_pkrtz(w10, w10));
        W11u = __builtin_bit_cast(unsigned, __builtin_amdgcn_cvt_pkrtz(w11, w11));
        O00 = (unsigned)(y0i * W_ + x0i) << 6;
        O01 = (unsigned)(y0i * W_ + x1i) << 6;
        O10 = (unsigned)(y1i * W_ + x0i) << 6;
        O11 = (unsigned)(y1i * W_ + x1i) << 6;
    }

    // gather own view's 4 corners x 4 quarters (quarter = immediate offset);
    // combine to per-view interp A[q][jj] (packed f16, r1-identical math)
    unsigned A[4][4];
    {
        const unsigned char* base = fb + (size_t)(b * V_ + j + 1) * HW_ * 64;
        half2_t Wa = __builtin_bit_cast(half2_t, W00u);
        half2_t Wb = __builtin_bit_cast(half2_t, W01u);
        half2_t Wc = __builtin_bit_cast(half2_t, W10u);
        half2_t Wd = __builtin_bit_cast(half2_t, W11u);
#pragma unroll
        for (int q = 0; q < 4; ++q) {
            uint4 c0 = *(const uint4*)(base + O00 + q * 16);
            uint4 c1 = *(const uint4*)(base + O01 + q * 16);
            uint4 c2 = *(const uint4*)(base + O10 + q * 16);
            uint4 c3 = *(const uint4*)(base + O11 + q * 16);
            unsigned u0[4] = {c0.x, c0.y, c0.z, c0.w};
            unsigned u1[4] = {c1.x, c1.y, c1.z, c1.w};
            unsigned u2[4] = {c2.x, c2.y, c2.z, c2.w};
            unsigned u3[4] = {c3.x, c3.y, c3.z, c3.w};
#pragma unroll
            for (int jj = 0; jj < 4; ++jj) {
                half2_t acc = __builtin_bit_cast(half2_t, u0[jj]) * Wa
                            + __builtin_bit_cast(half2_t, u1[jj]) * Wb
                            + __builtin_bit_cast(half2_t, u2[jj]) * Wc
                            + __builtin_bit_cast(half2_t, u3[jj]) * Wd;
                A[q][jj] = __builtin_bit_cast(unsigned, acc);
            }
        }
    }

    // 2-stage butterfly transpose across the quad (masks 1, 2).
    // After: lane j holds quarter j's interp from views {j, j^1, j^2, j^3}.
    const bool b0 = (j & 1) != 0;
    const bool b1 = (j & 2) != 0;
    unsigned Ra[2][4], Rb[2][4];              // [col-slot k][jj]: rows j, j^1
#pragma unroll
    for (int k = 0; k < 2; ++k)
#pragma unroll
        for (int jj = 0; jj < 4; ++jj) {
            unsigned snd = b0 ? A[2 * k][jj] : A[2 * k + 1][jj];
            unsigned rcv = (unsigned)__shfl_xor((int)snd, 1);
            Ra[k][jj] = b0 ? A[2 * k + 1][jj] : A[2 * k][jj];  // own row, col 2k+j0
            Rb[k][jj] = rcv;                                    // row j^1, col 2k+j0
        }
    unsigned B0[4], B1[4], B2[4], B3[4];      // views j, j^1, j^2, j^3 (any order ok)
#pragma unroll
    for (int jj = 0; jj < 4; ++jj) {
        unsigned sndA = b1 ? Ra[0][jj] : Ra[1][jj];
        unsigned sndB = b1 ? Rb[0][jj] : Rb[1][jj];
        B0[jj] = b1 ? Ra[1][jj] : Ra[0][jj];
        B1[jj] = b1 ? Rb[1][jj] : Rb[0][jj];
        B2[jj] = (unsigned)__shfl_xor((int)sndA, 2);
        B3[jj] = (unsigned)__shfl_xor((int)sndB, 2);
    }

    // accumulate s (sum) and q (sum of per-view squares), packed f16
#pragma unroll
    for (int jj = 0; jj < 4; ++jj) {
        half2_t v0 = __builtin_bit_cast(half2_t, B0[jj]);
        half2_t v1 = __builtin_bit_cast(half2_t, B1[jj]);
        half2_t v2 = __builtin_bit_cast(half2_t, B2[jj]);
        half2_t v3 = __builtin_bit_cast(half2_t, B3[jj]);
        s2[jj] += v0; s2[jj] += v1; s2[jj] += v2; s2[jj] += v3;
        q2[jj] += v0 * v0; q2[jj] += v1 * v1;
        q2[jj] += v2 * v2; q2[jj] += v3 * v3;
    }

    // variance for this thread's 8 channels, fully packed f16
    const _Float16 ivh = (_Float16)(1.0f / (float)V_);
    const half2_t iv2 = {ivh, ivh};
    unsigned pk[4];
#pragma unroll
    for (int jj = 0; jj < 4; ++jj) {
        half2_t ms = s2[jj] * iv2;
        half2_t var = q2[jj] * iv2 - ms * ms;
        pk[jj] = __builtin_bit_cast(unsigned, var);
    }

    // permute to B-fragment layout: target lane L gets (voxel L&15, quarter L>>4)
    // which lives in source lane (L&15)*4 + (L>>4)
    uint4 bu;
    {
        int srcl = ((lane & 15) << 2) + (lane >> 4);
        bu.x = (unsigned)__shfl((int)pk[0], srcl);
        bu.y = (unsigned)__shfl((int)pk[1], srcl);
        bu.z = (unsigned)__shfl((int)pk[2], srcl);
        bu.w = (unsigned)__shfl((int)pk[3], srcl);
    }
    half8_t bfrag = __builtin_bit_cast(half8_t, bu);
    half8_t afrag0 = __builtin_bit_cast(half8_t, a0u);
    half8_t afrag1 = __builtin_bit_cast(half8_t, a1u);

    floatx4 z = {0.f, 0.f, 0.f, 0.f};
    // D[m=tap][n=voxel-in-wave]; lane L: col=L&15, rows=(L>>4)*4+r
    floatx4 t0 = __builtin_amdgcn_mfma_f32_16x16x32_f16(afrag0, bfrag, z, 0, 0, 0);
    floatx4 t1 = __builtin_amdgcn_mfma_f32_16x16x32_f16(afrag1, bfrag, z, 0, 0, 0);

    // store taps as bf16 straight to the 27 T planes (pk-convert pairs, lo/hi stores)
    const unsigned gidx = (unsigned)(b * PLANE + d * HW_ + pixb + ((tid >> 6) << 4) + (lane & 15));
    const int tq = (lane >> 4) << 2;
    {
        unsigned u01 = cvt_pk_bf16(t0[0], t0[1]);
        unsigned u23 = cvt_pk_bf16(t0[2], t0[3]);
        T[(unsigned)((tq + 0) * NVOX) + gidx] = (unsigned short)(u01 & 0xffffu);
        T[(unsigned)((tq + 1) * NVOX) + gidx] = (unsigned short)(u01 >> 16);
        T[(unsigned)((tq + 2) * NVOX) + gidx] = (unsigned short)(u23 & 0xffffu);
        T[(unsigned)((tq + 3) * NVOX) + gidx] = (unsigned short)(u23 >> 16);
    }
    if (tq < 12) {                            // taps 16+tq .. min(19+tq,26)
        unsigned u01 = cvt_pk_bf16(t1[0], t1[1]);
        T[(unsigned)((16 + tq) * NVOX) + gidx] = (unsigned short)(u01 & 0xffffu);
        T[(unsigned)((17 + tq) * NVOX) + gidx] = (unsigned short)(u01 >> 16);
        if (tq < 8) {
            unsigned u23 = cvt_pk_bf16(t1[2], t1[3]);
            T[(unsigned)((18 + tq) * NVOX) + gidx] = (unsigned short)(u23 & 0xffffu);
            T[(unsigned)((19 + tq) * NVOX) + gidx] = (unsigned short)(u23 >> 16);
        } else {
            T[(unsigned)(26 * NVOX) + gidx] = (unsigned short)bf_rne(t1[2]);
        }
    }
}

// Vectorized cost: thread = 8 consecutive w-voxels (aligned; 8 | W). Per
// (kd,kh): 3 aligned uint4 loads (8 bf16 taps) + 2 predicated scalar edge
// loads; kw handled by register shifts.
__global__ __launch_bounds__(256) void cost_kernel(const unsigned short* __restrict__ T,
                                                   float* __restrict__ cost) {
    int t = blockIdx.x * 256 + threadIdx.x;    // over NVOX/8
    int v0 = t * 8;
    int w0 = v0 % W_;
    int h = (v0 / W_) % H_;
    int d = (v0 / HW_) % D_;
    int b = v0 / PLANE;
    float acc[8];
#pragma unroll
    for (int i = 0; i < 8; ++i) acc[i] = 0.f;

#pragma unroll
    for (int kd = 0; kd < 3; ++kd) {
        int dd = d + kd - 1;
        if (dd < 0 || dd >= D_) continue;
#pragma unroll
        for (int kh = 0; kh < 3; ++kh) {
            int hh = h + kh - 1;
            if (hh < 0 || hh >= H_) continue;
            unsigned r = (unsigned)(b * PLANE + dd * HW_ + hh * W_);
            int j = kd * 9 + kh * 3;
            const unsigned short* p0 = T + (size_t)j * NVOX + r;
            const unsigned short* p1 = p0 + NVOX;
            const unsigned short* p2 = p1 + NVOX;
            uint4 A0 = *(const uint4*)(p0 + w0);
            uint4 A1 = *(const uint4*)(p1 + w0);
            uint4 A2 = *(const uint4*)(p2 + w0);
            float eL = (w0 > 0) ? bflo((unsigned)p0[w0 - 1]) : 0.f;
            float eR = (w0 + 8 < W_) ? bflo((unsigned)p2[w0 + 8]) : 0.f;
            unsigned x0[4] = {A0.x, A0.y, A0.z, A0.w};
            unsigned x1[4] = {A1.x, A1.y, A1.z, A1.w};
            unsigned x2[4] = {A2.x, A2.y, A2.z, A2.w};
            float a0[8], a1[8], a2[8];
#pragma unroll
            for (int k = 0; k < 4; ++k) {
                a0[2 * k] = bflo(x0[k]); a0[2 * k + 1] = bfhi(x0[k]);
                a1[2 * k] = bflo(x1[k]); a1[2 * k + 1] = bfhi(x1[k]);
                a2[2 * k] = bflo(x2[k]); a2[2 * k + 1] = bfhi(x2[k]);
            }
            acc[0] += eL + a1[0] + a2[1];
#pragma unroll
            for (int i = 1; i < 7; ++i) acc[i] += a0[i - 1] + a1[i] + a2[i + 1];
            acc[7] += a0[6] + a1[7] + eR;
        }
    }
    float4* cp = (float4*)(cost + v0);
    cp[0] = make_float4(acc[0], acc[1], acc[2], acc[3]);
    cp[1] = make_float4(acc[4], acc[5], acc[6], acc[7]);
}

// Parallel softmax/depth/conf/itg: block = 64 pixels x 4 depth-quarters.
__global__ __launch_bounds__(256) void out_kernel(const float* __restrict__ cost,
                                                  const float* __restrict__ dv,
                                                  float* __restrict__ out) {
    __shared__ float red[4][64];
    const int tid = threadIdx.x;
    const int lane = tid & 63;
    const int wq = tid >> 6;                  // depth quarter
    const int pixg = blockIdx.x * 64 + lane;  // over B*HW
    const int b = pixg / HW_;
    const int pix = pixg - b * HW_;
    const float* cb = cost + (size_t)b * PLANE + pix;

    float p[12];
    float mx = -1e30f;
#pragma unroll
    for (int i = 0; i < 12; ++i) {
        p[i] = cb[(size_t)(wq * 12 + i) * HW_];
        mx = fmaxf(mx, p[i]);
    }
    red[wq][lane] = mx;
    __syncthreads();
    mx = fmaxf(fmaxf(red[0][lane], red[1][lane]), fmaxf(red[2][lane], red[3][lane]));
    float S = 0.f;
#pragma unroll
    for (int i = 0; i < 12; ++i) {
        p[i] = expf(p[i] - mx);
        S += p[i];
    }
    __syncthreads();
    red[wq][lane] = S;
    __syncthreads();
    S = red[0][lane] + red[1][lane] + red[2][lane] + red[3][lane];
    float invS = 1.f / S;
    float S2p = 0.f;
#pragma unroll
    for (int i = 0; i < 12; ++i) {
        p[i] *= invS;             // prob
        S2p += p[i];
    }
    __syncthreads();
    red[wq][lane] = S2p;
    __syncthreads();
    float S2 = red[0][lane] + red[1][lane] + red[2][lane] + red[3][lane];
    float invS2 = 1.f / fmaxf(S2, 1e-12f);
    float dp = 0.f, difp = 0.f;
#pragma unroll
    for (int i = 0; i < 12; ++i) {
        int d0 = wq * 12 + i;
        dp = fmaf(p[i] * invS2, dv[b * D_ + d0], dp);
        difp = fmaf(p[i], (float)d0, difp);
    }
    __syncthreads();
    red[wq][lane] = dp;
    __syncthreads();
    float depth = red[0][lane] + red[1][lane] + red[2][lane] + red[3][lane];
    __syncthreads();
    red[wq][lane] = difp;
    __syncthreads();
    float dif = red[0][lane] + red[1][lane] + red[2][lane] + red[3][lane];
    int di = (int)dif;
    di = min(max(di, 0), D_ - 1);
    float cf = 0.f;
#pragma unroll
    for (int i = 0; i < 12; ++i) {
        int d0 = wq * 12 + i;
        if (d0 >= di - 1 && d0 <= di + 2) cf += p[i];
    }
    __syncthreads();
    red[wq][lane] = cf;
    __syncthreads();
    float conf = red[0][lane] + red[1][lane] + red[2][lane] + red[3][lane];

    if (wq == 0) {
        out[pixg] = depth;
        out[B_ * HW_ + pixg] = conf;
    }
    float* itg = out + 2 * B_ * HW_ + (size_t)b * PLANE + pix;
#pragma unroll
    for (int i = 0; i < 12; ++i)
        itg[(size_t)(wq * 12 + i) * HW_] = p[i] * invS2;
}

extern "C" void kernel_launch(void* const* d_in, const int* in_sizes, int n_in,
                              void* d_out, int out_size, void* d_ws, size_t ws_size,
                              hipStream_t stream) {
    const float* feat = (const float*)d_in[0];   // (B,V,C,H,W)
    const float* proj = (const float*)d_in[1];   // (B,V,2,4,4)
    const float* dv   = (const float*)d_in[2];   // (B,D)
    const float* wreg = (const float*)d_in[3];   // (1,C,3,3,3)
    float* out = (float*)d_out;
    float* ws = (float*)d_ws;

    // workspace layout (floats)
    const size_t rt_off = 0;
    const size_t rt_sz = 128;
    const size_t wtb_off = rt_off + rt_sz;
    const size_t wtb_sz = 512;                            // 2*64*4 uints
    const size_t fcl_off = wtb_off + wtb_sz;
    const size_t fcl_sz = (size_t)B_ * V_ * HW_ * 16;     // fp16 pixels: 16 uints each
    const size_t T_off = fcl_off + fcl_sz;
    const size_t T_sz = (size_t)27 * NVOX / 2;            // bf16 taps (float-slots)
    const size_t cost_off = T_off + T_sz;
    const size_t cost_sz = (size_t)NVOX;
    const size_t need = (cost_off + cost_sz) * sizeof(float);
    if (ws_size < need) return;  // workspace too small — fail loudly

    float* rt = ws + rt_off;
    unsigned* wtb = (unsigned*)(ws + wtb_off);
    unsigned* feat_cl = (unsigned*)(ws + fcl_off);
    unsigned short* T = (unsigned short*)(ws + T_off);
    float* cost = ws + cost_off;

    setup_kernel<<<1, 128, 0, stream>>>(proj, wreg, rt, wtb);
    transpose_kernel<<<(B_ * V_ * HW_) / 256, 256, 0, stream>>>(feat, feat_cl);
    dim3 wgrid(HW_ / 64, D_, B_);
    warp_kernel<<<wgrid, 256, 0, stream>>>((const unsigned char*)feat_cl, rt, dv, wtb, T);
    cost_kernel<<<(NVOX / 8) / 256, 256, 0, stream>>>(T, cost);
    out_kernel<<<(B_ * HW_) / 64, 256, 0, stream>>>(cost, dv, out);
}

// Round 9
// 201.384 us; speedup vs baseline: 1.7438x; 1.7438x over previous
//
#include <hip/hip_runtime.h>
#include <math.h>

// Problem constants (from setup_inputs): B,V,C,D,H,W = 2,5,32,48,128,160
constexpr int B_ = 2;
constexpr int V_ = 5;
constexpr int C_ = 32;
constexpr int D_ = 48;
constexpr int H_ = 128;
constexpr int W_ = 160;
constexpr int HW_ = H_ * W_;               // 20480
constexpr int NVOX = B_ * D_ * HW_;        // 1,966,080
constexpr int PLANE = D_ * HW_;            // 983,040 (per-batch voxels)

typedef _Float16 half2_t __attribute__((ext_vector_type(2)));
typedef _Float16 half8_t __attribute__((ext_vector_type(8)));
typedef float floatx4 __attribute__((ext_vector_type(4)));

// ---------------- small matrix helpers (device) ----------------

__device__ inline void combine4(const float* pm, float out[4][4]) {
    const float* E = pm;
    const float* K = pm + 16;
    for (int i = 0; i < 3; ++i)
        for (int j = 0; j < 4; ++j) {
            float a = 0.f;
            for (int k = 0; k < 3; ++k) a += K[i * 4 + k] * E[k * 4 + j];
            out[i][j] = a;
        }
    for (int j = 0; j < 4; ++j) out[3][j] = E[12 + j];
}

__device__ inline void invert4(const float A[4][4], float inv[4][4]) {
    float M[4][8];
    for (int i = 0; i < 4; ++i)
        for (int j = 0; j < 4; ++j) {
            M[i][j] = A[i][j];
            M[i][4 + j] = (i == j) ? 1.f : 0.f;
        }
    for (int col = 0; col < 4; ++col) {
        int piv = col;
        float best = fabsf(M[col][col]);
        for (int r = col + 1; r < 4; ++r) {
            float v = fabsf(M[r][col]);
            if (v > best) { best = v; piv = r; }
        }
        if (piv != col)
            for (int j = 0; j < 8; ++j) { float t = M[col][j]; M[col][j] = M[piv][j]; M[piv][j] = t; }
        float ip = 1.f / M[col][col];
        for (int j = 0; j < 8; ++j) M[col][j] *= ip;
        for (int r = 0; r < 4; ++r) {
            if (r == col) continue;
            float f = M[r][col];
            for (int j = 0; j < 8; ++j) M[r][j] -= f * M[col][j];
        }
    }
    for (int i = 0; i < 4; ++i)
        for (int j = 0; j < 4; ++j) inv[i][j] = M[i][4 + j];
}

__device__ inline unsigned bf_rne(float f) {
    unsigned u = __float_as_uint(f);
    return (u + 0x7FFFu + ((u >> 16) & 1u)) >> 16;   // RNE (values are finite)
}

__device__ inline float bflo(unsigned u) { return __uint_as_float(u << 16); }
__device__ inline float bfhi(unsigned u) { return __uint_as_float(u & 0xffff0000u); }

__device__ inline unsigned h2pack(float a, float b) {   // fp16 RNE pair
    unsigned lo = (unsigned)__builtin_bit_cast(unsigned short, (_Float16)a);
    unsigned hi = (unsigned)__builtin_bit_cast(unsigned short, (_Float16)b);
    return lo | (hi << 16);
}

// pack two f32 -> two bf16 in one VALU op (RNE). No builtin on gfx950.
__device__ inline unsigned cvt_pk_bf16(float a, float b) {
    unsigned r;
    asm("v_cvt_pk_bf16_f32 %0, %1, %2" : "=v"(r) : "v"(a), "v"(b));
    return r;
}

// setup: (a) per b,v: P = src_proj @ inv(ref_proj) -> rt[12 floats]
//        (b) prepack conv weights as fp16 MFMA A-fragments:
//            A[m=tap=lane&15 (+16i)][k=ch=(lane>>4)*8+j], taps>=27 zero-padded
__global__ void setup_kernel(const float* __restrict__ proj, const float* __restrict__ wreg,
                             float* __restrict__ rt, unsigned* __restrict__ wtb) {
    int t = threadIdx.x;
    if (t < B_) {
        int b = t;
        float ref[4][4], inv[4][4];
        combine4(proj + (size_t)((b * V_ + 0) * 2) * 16, ref);
        invert4(ref, inv);
        for (int v = 1; v < V_; ++v) {
            float src[4][4];
            combine4(proj + (size_t)((b * V_ + v) * 2) * 16, src);
            float P[3][4];
            for (int i = 0; i < 3; ++i)
                for (int j = 0; j < 4; ++j) {
                    float a = 0.f;
                    for (int k = 0; k < 4; ++k) a += src[i][k] * inv[k][j];
                    P[i][j] = a;
                }
            float* o = rt + (size_t)(b * (V_ - 1) + (v - 1)) * 12;
            o[0] = P[0][0]; o[1] = P[0][1]; o[2] = P[0][2];
            o[3] = P[1][0]; o[4] = P[1][1]; o[5] = P[1][2];
            o[6] = P[2][0]; o[7] = P[2][1]; o[8] = P[2][2];
            o[9] = P[0][3]; o[10] = P[1][3]; o[11] = P[2][3];
        }
    }
    if (t < 128) {
        int i = t >> 6;          // which mfma (taps 0-15 / 16-31)
        int lane = t & 63;
        int q = lane >> 4;
        int l = lane & 15;
        int tap = i * 16 + l;
        unsigned u[4];
#pragma unroll
        for (int jj = 0; jj < 4; ++jj) {
            int ch0 = q * 8 + 2 * jj;
            float v0 = (tap < 27) ? wreg[ch0 * 27 + tap] : 0.f;
            float v1 = (tap < 27) ? wreg[(ch0 + 1) * 27 + tap] : 0.f;
            u[jj] = h2pack(v0, v1);
        }
        uint4* o = (uint4*)wtb;
        o[i * 64 + lane] = make_uint4(u[0], u[1], u[2], u[3]);
    }
}

// transpose features (B,V,C,H,W) f32 -> channel-last fp16 (B,V,H,W,C): 64 B/pixel
__global__ __launch_bounds__(256) void transpose_kernel(const float* __restrict__ feat,
                                                        unsigned* __restrict__ feat_cl) {
    int idx = blockIdx.x * 256 + threadIdx.x;  // over B*V*HW
    if (idx >= B_ * V_ * HW_) return;
    int pix = idx % HW_;
    int bv = idx / HW_;
    const float* src = feat + (size_t)bv * C_ * HW_ + pix;
    unsigned u[16];
#pragma unroll
    for (int j = 0; j < 16; ++j)
        u[j] = h2pack(src[(size_t)(2 * j) * HW_], src[(size_t)(2 * j + 1) * HW_]);
    uint4* dst = (uint4*)(feat_cl + (size_t)idx * 16);
    dst[0] = make_uint4(u[0], u[1], u[2], u[3]);
    dst[1] = make_uint4(u[4], u[5], u[6], u[7]);
    dst[2] = make_uint4(u[8], u[9], u[10], u[11]);
    dst[3] = make_uint4(u[12], u[13], u[14], u[15]);
}

// Fused homography warp + bilinear + variance + conv channel-reduction.
// Block = 256 threads = 64 pixels x 4 channel-quarter lanes; grid (320, D, B).
// v9: r7's gather pattern (quad lanes = same view, same corner pixel,
// adjacent quarters — the coalescing that r8 proved load-bearing) with the
// 4x-redundant projection replaced by LDS sharing: lane j=tid&3 computes
// ONLY view j's projection (r1/r7-verified math verbatim), writes 4 packed
// weights + 4 pixel byte-offsets (8 dwords) to sm[pixel][j]; after one
// __syncthreads(), every lane reads all 4 views' entries for its own pixel
// (quad lanes read identical addresses -> LDS broadcast) and adds its OWN
// cq16. Saves ~170 VALU insts/thread in a 95%-VALUBusy kernel.
// No DPP, no launch_bounds forcing (r2-r6 lessons).
// T layout: [j=0..26][b][d][h][w], ushort (bf16).
__global__ __launch_bounds__(256) void warp_kernel(const unsigned char* __restrict__ fb,
                                                   const float* __restrict__ rt,
                                                   const float* __restrict__ dv,
                                                   const unsigned* __restrict__ wtb,
                                                   unsigned short* __restrict__ T) {
    // per-pixel slot: 8 dwords payload, stride 36 dwords (144B: 16B-aligned,
    // rotates write banks across pixels)
    __shared__ __align__(16) unsigned sm[64 * 36];

    const int tid = threadIdx.x;
    const int lane = tid & 63;
    const int j = tid & 3;                    // channel quarter AND owned view
    const unsigned cq16 = (unsigned)j << 4;
    const int b = blockIdx.z;
    const int d = blockIdx.y;
    const int pixb = blockIdx.x * 64;         // block's first pixel
    const int pix = pixb + (tid >> 2);
    const int w = pix % W_;
    const int h = pix / W_;
    const float wf = (float)w, hf = (float)h;
    const float dep = dv[b * D_ + d];         // uniform -> s_load

    // A-fragments (fp16 conv weights), constant per lane
    const uint4* wp = (const uint4*)wtb;
    uint4 a0u = wp[lane];
    uint4 a1u = wp[64 + lane];

    // own-view projection (view j) — r1/r7-verified math verbatim
    unsigned W00u, W01u, W10u, W11u;          // half2 (w,w) per corner
    unsigned O00, O01, O10, O11;              // corner pixel byte offsets (no cq)
    {
        const float* m = rt + (b * (V_ - 1) + j) * 12;
        float xp = fmaf(fmaf(m[0], wf, fmaf(m[1], hf, m[2])), dep, m[9]);
        float yp = fmaf(fmaf(m[3], wf, fmaf(m[4], hf, m[5])), dep, m[10]);
        float zp = fmaf(fmaf(m[6], wf, fmaf(m[7], hf, m[8])), dep, m[11]);
        float iz = __builtin_amdgcn_rcpf(zp);
        float ix = xp * iz, iy = yp * iz;
        float x0f = floorf(ix), y0f = floorf(iy);
        float wx1 = ix - x0f, wx0 = 1.f - wx1;
        float wy1 = iy - y0f, wy0 = 1.f - wy1;
        float x1f = x0f + 1.f, y1f = y0f + 1.f;
        float wx0v = (x0f >= 0.f && x0f <= (float)(W_ - 1)) ? wx0 : 0.f;
        float wx1v = (x1f >= 0.f && x1f <= (float)(W_ - 1)) ? wx1 : 0.f;
        float wy0v = (y0f >= 0.f && y0f <= (float)(H_ - 1)) ? wy0 : 0.f;
        float wy1v = (y1f >= 0.f && y1f <= (float)(H_ - 1)) ? wy1 : 0.f;
        int x0i = (int)fminf(fmaxf(x0f, 0.f), (float)(W_ - 1));
        int x1i = (int)fminf(fmaxf(x1f, 0.f), (float)(W_ - 1));
        int y0i = (int)fminf(fmaxf(y0f, 0.f), (float)(H_ - 1));
        int y1i = (int)fminf(fmaxf(y1f, 0.f), (float)(H_ - 1));
        float w00 = wx0v * wy0v, w01 = wx1v * wy0v;
        float w10 = wx0v * wy1v, w11 = wx1v * wy1v;
        W00u = __builtin_bit_cast(unsigned, __builtin_amdgcn_cvt_pkrtz(w00, w00));
        W01u = __builtin_bit_cast(unsigned, __builtin_amdgcn_cvt_pkrtz(w01, w01));
        W10u = __builtin_bit_cast(unsigned, __builtin_amdgcn_cvt_pkrtz(w10, w10));
        W11u = __builtin_bit_cast(unsigned, __builtin_amdgcn_cvt_pkrtz(w11, w11));
        O00 = (unsigned)(y0i * W_ + x0i) << 6;
        O01 = (unsigned)(y0i * W_ + x1i) << 6;
        O10 = (unsigned)(y1i * W_ + x0i) << 6;
        O11 = (unsigned)(y1i * W_ + x1i) << 6;
    }

    // publish own view's weights+offsets for this pixel
    const unsigned base_l = (unsigned)(tid >> 2) * 36;
    {
        uint4* smw = (uint4*)(sm + base_l + (unsigned)j * 8);
        smw[0] = make_uint4(W00u, W01u, W10u, W11u);
        smw[1] = make_uint4(O00, O01, O10, O11);
    }

    // ref view: own pixel, own 8 channels; init packed f16 sum / sum-of-squares
    // (issued between LDS write and read — global load flies during the sync)
    half2_t s2[4], q2[4];
    {
        const unsigned char* rb = fb + (size_t)(b * V_) * HW_ * 64;
        uint4 r = *(const uint4*)(rb + (((unsigned)pix) << 6) + cq16);
        unsigned ru[4] = {r.x, r.y, r.z, r.w};
#pragma unroll
        for (int jj = 0; jj < 4; ++jj) {
            half2_t f = __builtin_bit_cast(half2_t, ru[jj]);
            s2[jj] = f;
            q2[jj] = f * f;
        }
    }

    __syncthreads();

    // per view: read its weights/offsets from LDS (quad-broadcast), gather
    // 4 corners (r7-identical coalesced pattern), combine (r7 math verbatim)
#pragma unroll
    for (int v = 0; v < 4; ++v) {
        const uint4* smr = (const uint4*)(sm + base_l + (unsigned)v * 8);
        uint4 Wp = smr[0];
        uint4 Op = smr[1];
        const unsigned char* base = fb + (size_t)(b * V_ + v + 1) * HW_ * 64;
        uint4 c0 = *(const uint4*)(base + (Op.x + cq16));
        uint4 c1 = *(const uint4*)(base + (Op.y + cq16));
        uint4 c2 = *(const uint4*)(base + (Op.z + cq16));
        uint4 c3 = *(const uint4*)(base + (Op.w + cq16));
        half2_t Wa = __builtin_bit_cast(half2_t, Wp.x);
        half2_t Wb = __builtin_bit_cast(half2_t, Wp.y);
        half2_t Wc = __builtin_bit_cast(half2_t, Wp.z);
        half2_t Wd = __builtin_bit_cast(half2_t, Wp.w);
        unsigned u0[4] = {c0.x, c0.y, c0.z, c0.w};
        unsigned u1[4] = {c1.x, c1.y, c1.z, c1.w};
        unsigned u2[4] = {c2.x, c2.y, c2.z, c2.w};
        unsigned u3[4] = {c3.x, c3.y, c3.z, c3.w};
#pragma unroll
        for (int jj = 0; jj < 4; ++jj) {
            half2_t acc = __builtin_bit_cast(half2_t, u0[jj]) * Wa
                        + __builtin_bit_cast(half2_t, u1[jj]) * Wb
                        + __builtin_bit_cast(half2_t, u2[jj]) * Wc
                        + __builtin_bit_cast(half2_t, u3[jj]) * Wd;
            s2[jj] += acc;                    // v_pk_add_f16
            q2[jj] += acc * acc;              // v_pk_fma_f16
        }
    }

    // variance for this thread's 8 channels, fully packed f16
    const _Float16 ivh = (_Float16)(1.0f / (float)V_);
    const half2_t iv2 = {ivh, ivh};
    unsigned pk[4];
#pragma unroll
    for (int jj = 0; jj < 4; ++jj) {
        half2_t ms = s2[jj] * iv2;
        half2_t var = q2[jj] * iv2 - ms * ms;
        pk[jj] = __builtin_bit_cast(unsigned, var);
    }

    // permute to B-fragment layout: target lane L gets (voxel L&15, quarter L>>4)
    // which lives in source lane (L&15)*4 + (L>>4)
    uint4 bu;
    {
        int srcl = ((lane & 15) << 2) + (lane >> 4);
        bu.x = (unsigned)__shfl((int)pk[0], srcl);
        bu.y = (unsigned)__shfl((int)pk[1], srcl);
        bu.z = (unsigned)__shfl((int)pk[2], srcl);
        bu.w = (unsigned)__shfl((int)pk[3], srcl);
    }
    half8_t bfrag = __builtin_bit_cast(half8_t, bu);
    half8_t afrag0 = __builtin_bit_cast(half8_t, a0u);
    half8_t afrag1 = __builtin_bit_cast(half8_t, a1u);

    floatx4 z = {0.f, 0.f, 0.f, 0.f};
    // D[m=tap][n=voxel-in-wave]; lane L: col=L&15, rows=(L>>4)*4+r
    floatx4 t0 = __builtin_amdgcn_mfma_f32_16x16x32_f16(afrag0, bfrag, z, 0, 0, 0);
    floatx4 t1 = __builtin_amdgcn_mfma_f32_16x16x32_f16(afrag1, bfrag, z, 0, 0, 0);

    // store taps as bf16 straight to the 27 T planes (pk-convert pairs, lo/hi stores)
    const unsigned gidx = (unsigned)(b * PLANE + d * HW_ + pixb + ((tid >> 6) << 4) + (lane & 15));
    const int tq = (lane >> 4) << 2;
    {
        unsigned u01 = cvt_pk_bf16(t0[0], t0[1]);
        unsigned u23 = cvt_pk_bf16(t0[2], t0[3]);
        T[(unsigned)((tq + 0) * NVOX) + gidx] = (unsigned short)(u01 & 0xffffu);
        T[(unsigned)((tq + 1) * NVOX) + gidx] = (unsigned short)(u01 >> 16);
        T[(unsigned)((tq + 2) * NVOX) + gidx] = (unsigned short)(u23 & 0xffffu);
        T[(unsigned)((tq + 3) * NVOX) + gidx] = (unsigned short)(u23 >> 16);
    }
    if (tq < 12) {                            // taps 16+tq .. min(19+tq,26)
        unsigned u01 = cvt_pk_bf16(t1[0], t1[1]);
        T[(unsigned)((16 + tq) * NVOX) + gidx] = (unsigned short)(u01 & 0xffffu);
        T[(unsigned)((17 + tq) * NVOX) + gidx] = (unsigned short)(u01 >> 16);
        if (tq < 8) {
            unsigned u23 = cvt_pk_bf16(t1[2], t1[3]);
            T[(unsigned)((18 + tq) * NVOX) + gidx] = (unsigned short)(u23 & 0xffffu);
            T[(unsigned)((19 + tq) * NVOX) + gidx] = (unsigned short)(u23 >> 16);
        } else {
            T[(unsigned)(26 * NVOX) + gidx] = (unsigned short)bf_rne(t1[2]);
        }
    }
}

// Vectorized cost: thread = 8 consecutive w-voxels (aligned; 8 | W). Per
// (kd,kh): 3 aligned uint4 loads (8 bf16 taps) + 2 predicated scalar edge
// loads; kw handled by register shifts.
__global__ __launch_bounds__(256) void cost_kernel(const unsigned short* __restrict__ T,
                                                   float* __restrict__ cost) {
    int t = blockIdx.x * 256 + threadIdx.x;    // over NVOX/8
    int v0 = t * 8;
    int w0 = v0 % W_;
    int h = (v0 / W_) % H_;
    int d = (v0 / HW_) % D_;
    int b = v0 / PLANE;
    float acc[8];
#pragma unroll
    for (int i = 0; i < 8; ++i) acc[i] = 0.f;

#pragma unroll
    for (int kd = 0; kd < 3; ++kd) {
        int dd = d + kd - 1;
        if (dd < 0 || dd >= D_) continue;
#pragma unroll
        for (int kh = 0; kh < 3; ++kh) {
            int hh = h + kh - 1;
            if (hh < 0 || hh >= H_) continue;
            unsigned r = (unsigned)(b * PLANE + dd * HW_ + hh * W_);
            int j = kd * 9 + kh * 3;
            const unsigned short* p0 = T + (size_t)j * NVOX + r;
            const unsigned short* p1 = p0 + NVOX;
            const unsigned short* p2 = p1 + NVOX;
            uint4 A0 = *(const uint4*)(p0 + w0);
            uint4 A1 = *(const uint4*)(p1 + w0);
            uint4 A2 = *(const uint4*)(p2 + w0);
            float eL = (w0 > 0) ? bflo((unsigned)p0[w0 - 1]) : 0.f;
            float eR = (w0 + 8 < W_) ? bflo((unsigned)p2[w0 + 8]) : 0.f;
            unsigned x0[4] = {A0.x, A0.y, A0.z, A0.w};
            unsigned x1[4] = {A1.x, A1.y, A1.z, A1.w};
            unsigned x2[4] = {A2.x, A2.y, A2.z, A2.w};
            float a0[8], a1[8], a2[8];
#pragma unroll
            for (int k = 0; k < 4; ++k) {
                a0[2 * k] = bflo(x0[k]); a0[2 * k + 1] = bfhi(x0[k]);
                a1[2 * k] = bflo(x1[k]); a1[2 * k + 1] = bfhi(x1[k]);
                a2[2 * k] = bflo(x2[k]); a2[2 * k + 1] = bfhi(x2[k]);
            }
            acc[0] += eL + a1[0] + a2[1];
#pragma unroll
            for (int i = 1; i < 7; ++i) acc[i] += a0[i - 1] + a1[i] + a2[i + 1];
            acc[7] += a0[6] + a1[7] + eR;
        }
    }
    float4* cp = (float4*)(cost + v0);
    cp[0] = make_float4(acc[0], acc[1], acc[2], acc[3]);
    cp[1] = make_float4(acc[4], acc[5], acc[6], acc[7]);
}

// Parallel softmax/depth/conf/itg: block = 64 pixels x 4 depth-quarters.
__global__ __launch_bounds__(256) void out_kernel(const float* __restrict__ cost,
                                                  const float* __restrict__ dv,
                                                  float* __restrict__ out) {
    __shared__ float red[4][64];
    const int tid = threadIdx.x;
    const int lane = tid & 63;
    const int wq = tid >> 6;                  // depth quarter
    const int pixg = blockIdx.x * 64 + lane;  // over B*HW
    const int b = pixg / HW_;
    const int pix = pixg - b * HW_;
    const float* cb = cost + (size_t)b * PLANE + pix;

    float p[12];
    float mx = -1e30f;
#pragma unroll
    for (int i = 0; i < 12; ++i) {
        p[i] = cb[(size_t)(wq * 12 + i) * HW_];
        mx = fmaxf(mx, p[i]);
    }
    red[wq][lane] = mx;
    __syncthreads();
    mx = fmaxf(fmaxf(red[0][lane], red[1][lane]), fmaxf(red[2][lane], red[3][lane]));
    float S = 0.f;
#pragma unroll
    for (int i = 0; i < 12; ++i) {
        p[i] = expf(p[i] - mx);
        S += p[i];
    }
    __syncthreads();
    red[wq][lane] = S;
    __syncthreads();
    S = red[0][lane] + red[1][lane] + red[2][lane] + red[3][lane];
    float invS = 1.f / S;
    float S2p = 0.f;
#pragma unroll
    for (int i = 0; i < 12; ++i) {
        p[i] *= invS;             // prob
        S2p += p[i];
    }
    __syncthreads();
    red[wq][lane] = S2p;
    __syncthreads();
    float S2 = red[0][lane] + red[1][lane] + red[2][lane] + red[3][lane];
    float invS2 = 1.f / fmaxf(S2, 1e-12f);
    float dp = 0.f, difp = 0.f;
#pragma unroll
    for (int i = 0; i < 12; ++i) {
        int d0 = wq * 12 + i;
        dp = fmaf(p[i] * invS2, dv[b * D_ + d0], dp);
        difp = fmaf(p[i], (float)d0, difp);
    }
    __syncthreads();
    red[wq][lane] = dp;
    __syncthreads();
    float depth = red[0][lane] + red[1][lane] + red[2][lane] + red[3][lane];
    __syncthreads();
    red[wq][lane] = difp;
    __syncthreads();
    float dif = red[0][lane] + red[1][lane] + red[2][lane] + red[3][lane];
    int di = (int)dif;
    di = min(max(di, 0), D_ - 1);
    float cf = 0.f;
#pragma unroll
    for (int i = 0; i < 12; ++i) {
        int d0 = wq * 12 + i;
        if (d0 >= di - 1 && d0 <= di + 2) cf += p[i];
    }
    __syncthreads();
    red[wq][lane] = cf;
    __syncthreads();
    float conf = red[0][lane] + red[1][lane] + red[2][lane] + red[3][lane];

    if (wq == 0) {
        out[pixg] = depth;
        out[B_ * HW_ + pixg] = conf;
    }
    float* itg = out + 2 * B_ * HW_ + (size_t)b * PLANE + pix;
#pragma unroll
    for (int i = 0; i < 12; ++i)
        itg[(size_t)(wq * 12 + i) * HW_] = p[i] * invS2;
}

extern "C" void kernel_launch(void* const* d_in, const int* in_sizes, int n_in,
                              void* d_out, int out_size, void* d_ws, size_t ws_size,
                              hipStream_t stream) {
    const float* feat = (const float*)d_in[0];   // (B,V,C,H,W)
    const float* proj = (const float*)d_in[1];   // (B,V,2,4,4)
    const float* dv   = (const float*)d_in[2];   // (B,D)
    const float* wreg = (const float*)d_in[3];   // (1,C,3,3,3)
    float* out = (float*)d_out;
    float* ws = (float*)d_ws;

    // workspace layout (floats)
    const size_t rt_off = 0;
    const size_t rt_sz = 128;
    const size_t wtb_off = rt_off + rt_sz;
    const size_t wtb_sz = 512;                            // 2*64*4 uints
    const size_t fcl_off = wtb_off + wtb_sz;
    const size_t fcl_sz = (size_t)B_ * V_ * HW_ * 16;     // fp16 pixels: 16 uints each
    const size_t T_off = fcl_off + fcl_sz;
    const size_t T_sz = (size_t)27 * NVOX / 2;            // bf16 taps (float-slots)
    const size_t cost_off = T_off + T_sz;
    const size_t cost_sz = (size_t)NVOX;
    const size_t need = (cost_off + cost_sz) * sizeof(float);
    if (ws_size < need) return;  // workspace too small — fail loudly

    float* rt = ws + rt_off;
    unsigned* wtb = (unsigned*)(ws + wtb_off);
    unsigned* feat_cl = (unsigned*)(ws + fcl_off);
    unsigned short* T = (unsigned short*)(ws + T_off);
    float* cost = ws + cost_off;

    setup_kernel<<<1, 128, 0, stream>>>(proj, wreg, rt, wtb);
    transpose_kernel<<<(B_ * V_ * HW_) / 256, 256, 0, stream>>>(feat, feat_cl);
    dim3 wgrid(HW_ / 64, D_, B_);
    warp_kernel<<<wgrid, 256, 0, stream>>>((const unsigned char*)feat_cl, rt, dv, wtb, T);
    cost_kernel<<<(NVOX / 8) / 256, 256, 0, stream>>>(T, cost);
    out_kernel<<<(B_ * HW_) / 64, 256, 0, stream>>>(cost, dv, out);
}

// Round 10
// 194.744 us; speedup vs baseline: 1.8032x; 1.0341x over previous
//
#include <hip/hip_runtime.h>
#include <math.h>

// Problem constants (from setup_inputs): B,V,C,D,H,W = 2,5,32,48,128,160
constexpr int B_ = 2;
constexpr int V_ = 5;
constexpr int C_ = 32;
constexpr int D_ = 48;
constexpr int H_ = 128;
constexpr int W_ = 160;
constexpr int HW_ = H_ * W_;               // 20480
constexpr int NVOX = B_ * D_ * HW_;        // 1,966,080
constexpr int PLANE = D_ * HW_;            // 983,040 (per-batch voxels)

typedef _Float16 half2_t __attribute__((ext_vector_type(2)));
typedef _Float16 half8_t __attribute__((ext_vector_type(8)));
typedef float floatx4 __attribute__((ext_vector_type(4)));

// ---------------- small matrix helpers (device) ----------------

__device__ inline void combine4(const float* pm, float out[4][4]) {
    const float* E = pm;
    const float* K = pm + 16;
    for (int i = 0; i < 3; ++i)
        for (int j = 0; j < 4; ++j) {
            float a = 0.f;
            for (int k = 0; k < 3; ++k) a += K[i * 4 + k] * E[k * 4 + j];
            out[i][j] = a;
        }
    for (int j = 0; j < 4; ++j) out[3][j] = E[12 + j];
}

__device__ inline void invert4(const float A[4][4], float inv[4][4]) {
    float M[4][8];
    for (int i = 0; i < 4; ++i)
        for (int j = 0; j < 4; ++j) {
            M[i][j] = A[i][j];
            M[i][4 + j] = (i == j) ? 1.f : 0.f;
        }
    for (int col = 0; col < 4; ++col) {
        int piv = col;
        float best = fabsf(M[col][col]);
        for (int r = col + 1; r < 4; ++r) {
            float v = fabsf(M[r][col]);
            if (v > best) { best = v; piv = r; }
        }
        if (piv != col)
            for (int j = 0; j < 8; ++j) { float t = M[col][j]; M[col][j] = M[piv][j]; M[piv][j] = t; }
        float ip = 1.f / M[col][col];
        for (int j = 0; j < 8; ++j) M[col][j] *= ip;
        for (int r = 0; r < 4; ++r) {
            if (r == col) continue;
            float f = M[r][col];
            for (int j = 0; j < 8; ++j) M[r][j] -= f * M[col][j];
        }
    }
    for (int i = 0; i < 4; ++i)
        for (int j = 0; j < 4; ++j) inv[i][j] = M[i][4 + j];
}

__device__ inline unsigned bf_rne(float f) {
    unsigned u = __float_as_uint(f);
    return (u + 0x7FFFu + ((u >> 16) & 1u)) >> 16;   // RNE (values are finite)
}

__device__ inline float bflo(unsigned u) { return __uint_as_float(u << 16); }
__device__ inline float bfhi(unsigned u) { return __uint_as_float(u & 0xffff0000u); }

__device__ inline unsigned h2pack(float a, float b) {   // fp16 RNE pair
    unsigned lo = (unsigned)__builtin_bit_cast(unsigned short, (_Float16)a);
    unsigned hi = (unsigned)__builtin_bit_cast(unsigned short, (_Float16)b);
    return lo | (hi << 16);
}

// pack two f32 -> two bf16 in one VALU op (RNE). No builtin on gfx950.
__device__ inline unsigned cvt_pk_bf16(float a, float b) {
    unsigned r;
    asm("v_cvt_pk_bf16_f32 %0, %1, %2" : "=v"(r) : "v"(a), "v"(b));
    return r;
}

// setup: (a) per b,v: P = src_proj @ inv(ref_proj) -> rt[12 floats]
//        (b) prepack conv weights as fp16 MFMA A-fragments:
//            A[m=tap=lane&15 (+16i)][k=ch=(lane>>4)*8+j], taps>=27 zero-padded
__global__ void setup_kernel(const float* __restrict__ proj, const float* __restrict__ wreg,
                             float* __restrict__ rt, unsigned* __restrict__ wtb) {
    int t = threadIdx.x;
    if (t < B_) {
        int b = t;
        float ref[4][4], inv[4][4];
        combine4(proj + (size_t)((b * V_ + 0) * 2) * 16, ref);
        invert4(ref, inv);
        for (int v = 1; v < V_; ++v) {
            float src[4][4];
            combine4(proj + (size_t)((b * V_ + v) * 2) * 16, src);
            float P[3][4];
            for (int i = 0; i < 3; ++i)
                for (int j = 0; j < 4; ++j) {
                    float a = 0.f;
                    for (int k = 0; k < 4; ++k) a += src[i][k] * inv[k][j];
                    P[i][j] = a;
                }
            float* o = rt + (size_t)(b * (V_ - 1) + (v - 1)) * 12;
            o[0] = P[0][0]; o[1] = P[0][1]; o[2] = P[0][2];
            o[3] = P[1][0]; o[4] = P[1][1]; o[5] = P[1][2];
            o[6] = P[2][0]; o[7] = P[2][1]; o[8] = P[2][2];
            o[9] = P[0][3]; o[10] = P[1][3]; o[11] = P[2][3];
        }
    }
    if (t < 128) {
        int i = t >> 6;          // which mfma (taps 0-15 / 16-31)
        int lane = t & 63;
        int q = lane >> 4;
        int l = lane & 15;
        int tap = i * 16 + l;
        unsigned u[4];
#pragma unroll
        for (int jj = 0; jj < 4; ++jj) {
            int ch0 = q * 8 + 2 * jj;
            float v0 = (tap < 27) ? wreg[ch0 * 27 + tap] : 0.f;
            float v1 = (tap < 27) ? wreg[(ch0 + 1) * 27 + tap] : 0.f;
            u[jj] = h2pack(v0, v1);
        }
        uint4* o = (uint4*)wtb;
        o[i * 64 + lane] = make_uint4(u[0], u[1], u[2], u[3]);
    }
}

// transpose features (B,V,C,H,W) f32 -> channel-last fp16 (B,V,H,W,C): 64 B/pixel
__global__ __launch_bounds__(256) void transpose_kernel(const float* __restrict__ feat,
                                                        unsigned* __restrict__ feat_cl) {
    int idx = blockIdx.x * 256 + threadIdx.x;  // over B*V*HW
    if (idx >= B_ * V_ * HW_) return;
    int pix = idx % HW_;
    int bv = idx / HW_;
    const float* src = feat + (size_t)bv * C_ * HW_ + pix;
    unsigned u[16];
#pragma unroll
    for (int j = 0; j < 16; ++j)
        u[j] = h2pack(src[(size_t)(2 * j) * HW_], src[(size_t)(2 * j + 1) * HW_]);
    uint4* dst = (uint4*)(feat_cl + (size_t)idx * 16);
    dst[0] = make_uint4(u[0], u[1], u[2], u[3]);
    dst[1] = make_uint4(u[4], u[5], u[6], u[7]);
    dst[2] = make_uint4(u[8], u[9], u[10], u[11]);
    dst[3] = make_uint4(u[12], u[13], u[14], u[15]);
}

// Fused homography warp + bilinear + variance + conv channel-reduction.
// Block = 256 threads = 64 pixels x 4 channel-quarter lanes; grid (320, 24, B)
// — each block processes TWO depth planes (d0, d0+1) of the same 64 pixels.
// v10 = r9's LDS projection-sharing + depth-pairing: lane j=tid&3 computes
// view j's projection for BOTH depths (rot-dot products shared; 2nd depth
// costs ~40 ops), publishes 16 dwords to sm[pixel][j]; after one sync, each
// lane reads all 4 views' entries for its pixel (quad-broadcast) and per view
// issues 8 gathers (2 depths x 4 corners — two independent chains double the
// memory parallelism hiding LDS+L2 latency). Ref load/decode, A-frags, pixel
// math, sync amortized over 2 voxels. Gather pattern per depth is r7's
// coalesced one (quad lanes = same corner pixel, adjacent quarters — r8
// proved this load-bearing). No DPP, no launch_bounds forcing (r2-r6).
// T layout: [j=0..26][b][d][h][w], ushort (bf16).
__global__ __launch_bounds__(256) void warp_kernel(const unsigned char* __restrict__ fb,
                                                   const float* __restrict__ rt,
                                                   const float* __restrict__ dv,
                                                   const unsigned* __restrict__ wtb,
                                                   unsigned short* __restrict__ T) {
    // per-pixel slot: 4 views x 16 dwords payload; stride 68 dwords (272B,
    // 16B-aligned, rotates banks across pixels). 64*68*4 = 17408 B.
    __shared__ __align__(16) unsigned sm[64 * 68];

    const int tid = threadIdx.x;
    const int lane = tid & 63;
    const int j = tid & 3;                    // channel quarter AND owned view
    const unsigned cq16 = (unsigned)j << 4;
    const int b = blockIdx.z;
    const int d0 = blockIdx.y * 2;            // this block's two depths
    const int pixb = blockIdx.x * 64;         // block's first pixel
    const int pix = pixb + (tid >> 2);
    const int w = pix % W_;
    const int h = pix / W_;
    const float wf = (float)w, hf = (float)h;
    const float depA = dv[b * D_ + d0];       // uniform -> s_load
    const float depB = dv[b * D_ + d0 + 1];

    // A-fragments (fp16 conv weights), constant per lane
    const uint4* wp = (const uint4*)wtb;
    uint4 a0u = wp[lane];
    uint4 a1u = wp[64 + lane];

    // own-view projection (view j), both depths. rot-dot products shared.
    unsigned WA[4], OA[4], WB[4], OB[4];
    {
        const float* m = rt + (b * (V_ - 1) + j) * 12;
        float rx = fmaf(m[0], wf, fmaf(m[1], hf, m[2]));
        float ry = fmaf(m[3], wf, fmaf(m[4], hf, m[5]));
        float rz = fmaf(m[6], wf, fmaf(m[7], hf, m[8]));
#pragma unroll
        for (int k = 0; k < 2; ++k) {
            float dep = k ? depB : depA;
            unsigned* Wo = k ? WB : WA;
            unsigned* Oo = k ? OB : OA;
            float xp = fmaf(rx, dep, m[9]);
            float yp = fmaf(ry, dep, m[10]);
            float zp = fmaf(rz, dep, m[11]);
            float iz = __builtin_amdgcn_rcpf(zp);
            float ix = xp * iz, iy = yp * iz;
            float x0f = floorf(ix), y0f = floorf(iy);
            float wx1 = ix - x0f, wx0 = 1.f - wx1;
            float wy1 = iy - y0f, wy0 = 1.f - wy1;
            float x1f = x0f + 1.f, y1f = y0f + 1.f;
            float wx0v = (x0f >= 0.f && x0f <= (float)(W_ - 1)) ? wx0 : 0.f;
            float wx1v = (x1f >= 0.f && x1f <= (float)(W_ - 1)) ? wx1 : 0.f;
            float wy0v = (y0f >= 0.f && y0f <= (float)(H_ - 1)) ? wy0 : 0.f;
            float wy1v = (y1f >= 0.f && y1f <= (float)(H_ - 1)) ? wy1 : 0.f;
            int x0i = (int)fminf(fmaxf(x0f, 0.f), (float)(W_ - 1));
            int x1i = (int)fminf(fmaxf(x1f, 0.f), (float)(W_ - 1));
            int y0i = (int)fminf(fmaxf(y0f, 0.f), (float)(H_ - 1));
            int y1i = (int)fminf(fmaxf(y1f, 0.f), (float)(H_ - 1));
            float w00 = wx0v * wy0v, w01 = wx1v * wy0v;
            float w10 = wx0v * wy1v, w11 = wx1v * wy1v;
            Wo[0] = __builtin_bit_cast(unsigned, __builtin_amdgcn_cvt_pkrtz(w00, w00));
            Wo[1] = __builtin_bit_cast(unsigned, __builtin_amdgcn_cvt_pkrtz(w01, w01));
            Wo[2] = __builtin_bit_cast(unsigned, __builtin_amdgcn_cvt_pkrtz(w10, w10));
            Wo[3] = __builtin_bit_cast(unsigned, __builtin_amdgcn_cvt_pkrtz(w11, w11));
            Oo[0] = (unsigned)(y0i * W_ + x0i) << 6;
            Oo[1] = (unsigned)(y0i * W_ + x1i) << 6;
            Oo[2] = (unsigned)(y1i * W_ + x0i) << 6;
            Oo[3] = (unsigned)(y1i * W_ + x1i) << 6;
        }
    }

    // publish own view's weights+offsets (both depths) for this pixel
    const unsigned base_l = (unsigned)(tid >> 2) * 68;
    {
        uint4* smw = (uint4*)(sm + base_l + (unsigned)j * 16);
        smw[0] = make_uint4(WA[0], WA[1], WA[2], WA[3]);
        smw[1] = make_uint4(OA[0], OA[1], OA[2], OA[3]);
        smw[2] = make_uint4(WB[0], WB[1], WB[2], WB[3]);
        smw[3] = make_uint4(OB[0], OB[1], OB[2], OB[3]);
    }

    // ref view: own pixel, own 8 channels — shared by BOTH depths
    half2_t sA[4], qA[4], sB[4], qB[4];
    {
        const unsigned char* rb = fb + (size_t)(b * V_) * HW_ * 64;
        uint4 r = *(const uint4*)(rb + (((unsigned)pix) << 6) + cq16);
        unsigned ru[4] = {r.x, r.y, r.z, r.w};
#pragma unroll
        for (int jj = 0; jj < 4; ++jj) {
            half2_t f = __builtin_bit_cast(half2_t, ru[jj]);
            sA[jj] = f;  qA[jj] = f * f;
            sB[jj] = f;  qB[jj] = f * f;
        }
    }

    __syncthreads();

    // per view: read weights/offsets for both depths (quad-broadcast LDS),
    // issue 8 gathers (2 independent depth chains), combine both depths
#pragma unroll
    for (int v = 0; v < 4; ++v) {
        const uint4* smr = (const uint4*)(sm + base_l + (unsigned)v * 16);
        uint4 WpA = smr[0];
        uint4 OpA = smr[1];
        uint4 WpB = smr[2];
        uint4 OpB = smr[3];
        const unsigned char* base = fb + (size_t)(b * V_ + v + 1) * HW_ * 64;
        uint4 a0 = *(const uint4*)(base + (OpA.x + cq16));
        uint4 a1 = *(const uint4*)(base + (OpA.y + cq16));
        uint4 a2 = *(const uint4*)(base + (OpA.z + cq16));
        uint4 a3 = *(const uint4*)(base + (OpA.w + cq16));
        uint4 b0 = *(const uint4*)(base + (OpB.x + cq16));
        uint4 b1 = *(const uint4*)(base + (OpB.y + cq16));
        uint4 b2 = *(const uint4*)(base + (OpB.z + cq16));
        uint4 b3 = *(const uint4*)(base + (OpB.w + cq16));
        {
            half2_t Wa = __builtin_bit_cast(half2_t, WpA.x);
            half2_t Wb = __builtin_bit_cast(half2_t, WpA.y);
            half2_t Wc = __builtin_bit_cast(half2_t, WpA.z);
            half2_t Wd = __builtin_bit_cast(half2_t, WpA.w);
            unsigned u0[4] = {a0.x, a0.y, a0.z, a0.w};
            unsigned u1[4] = {a1.x, a1.y, a1.z, a1.w};
            unsigned u2[4] = {a2.x, a2.y, a2.z, a2.w};
            unsigned u3[4] = {a3.x, a3.y, a3.z, a3.w};
#pragma unroll
            for (int jj = 0; jj < 4; ++jj) {
                half2_t acc = __builtin_bit_cast(half2_t, u0[jj]) * Wa
                            + __builtin_bit_cast(half2_t, u1[jj]) * Wb
                            + __builtin_bit_cast(half2_t, u2[jj]) * Wc
                            + __builtin_bit_cast(half2_t, u3[jj]) * Wd;
                sA[jj] += acc;
                qA[jj] += acc * acc;
            }
        }
        {
            half2_t Wa = __builtin_bit_cast(half2_t, WpB.x);
            half2_t Wb = __builtin_bit_cast(half2_t, WpB.y);
            half2_t Wc = __builtin_bit_cast(half2_t, WpB.z);
            half2_t Wd = __builtin_bit_cast(half2_t, WpB.w);
            unsigned u0[4] = {b0.x, b0.y, b0.z, b0.w};
            unsigned u1[4] = {b1.x, b1.y, b1.z, b1.w};
            unsigned u2[4] = {b2.x, b2.y, b2.z, b2.w};
            unsigned u3[4] = {b3.x, b3.y, b3.z, b3.w};
#pragma unroll
            for (int jj = 0; jj < 4; ++jj) {
                half2_t acc = __builtin_bit_cast(half2_t, u0[jj]) * Wa
                            + __builtin_bit_cast(half2_t, u1[jj]) * Wb
                            + __builtin_bit_cast(half2_t, u2[jj]) * Wc
                            + __builtin_bit_cast(half2_t, u3[jj]) * Wd;
                sB[jj] += acc;
                qB[jj] += acc * acc;
            }
        }
    }

    // epilogue per depth: variance (packed f16), B-frag shuffle, MFMA, stores
    const _Float16 ivh = (_Float16)(1.0f / (float)V_);
    const half2_t iv2 = {ivh, ivh};
    half8_t afrag0 = __builtin_bit_cast(half8_t, a0u);
    half8_t afrag1 = __builtin_bit_cast(half8_t, a1u);
    const int srcl = ((lane & 15) << 2) + (lane >> 4);
    const int tq = (lane >> 4) << 2;

#pragma unroll
    for (int k = 0; k < 2; ++k) {
        unsigned pk[4];
#pragma unroll
        for (int jj = 0; jj < 4; ++jj) {
            half2_t s2 = k ? sB[jj] : sA[jj];
            half2_t q2 = k ? qB[jj] : qA[jj];
            half2_t ms = s2 * iv2;
            half2_t var = q2 * iv2 - ms * ms;
            pk[jj] = __builtin_bit_cast(unsigned, var);
        }
        uint4 bu;
        bu.x = (unsigned)__shfl((int)pk[0], srcl);
        bu.y = (unsigned)__shfl((int)pk[1], srcl);
        bu.z = (unsigned)__shfl((int)pk[2], srcl);
        bu.w = (unsigned)__shfl((int)pk[3], srcl);
        half8_t bfrag = __builtin_bit_cast(half8_t, bu);

        floatx4 z = {0.f, 0.f, 0.f, 0.f};
        floatx4 t0 = __builtin_amdgcn_mfma_f32_16x16x32_f16(afrag0, bfrag, z, 0, 0, 0);
        floatx4 t1 = __builtin_amdgcn_mfma_f32_16x16x32_f16(afrag1, bfrag, z, 0, 0, 0);

        const unsigned gidx = (unsigned)(b * PLANE + (d0 + k) * HW_ + pixb +
                                         ((tid >> 6) << 4) + (lane & 15));
        {
            unsigned u01 = cvt_pk_bf16(t0[0], t0[1]);
            unsigned u23 = cvt_pk_bf16(t0[2], t0[3]);
            T[(unsigned)((tq + 0) * NVOX) + gidx] = (unsigned short)(u01 & 0xffffu);
            T[(unsigned)((tq + 1) * NVOX) + gidx] = (unsigned short)(u01 >> 16);
            T[(unsigned)((tq + 2) * NVOX) + gidx] = (unsigned short)(u23 & 0xffffu);
            T[(unsigned)((tq + 3) * NVOX) + gidx] = (unsigned short)(u23 >> 16);
        }
        if (tq < 12) {                        // taps 16+tq .. min(19+tq,26)
            unsigned u01 = cvt_pk_bf16(t1[0], t1[1]);
            T[(unsigned)((16 + tq) * NVOX) + gidx] = (unsigned short)(u01 & 0xffffu);
            T[(unsigned)((17 + tq) * NVOX) + gidx] = (unsigned short)(u01 >> 16);
            if (tq < 8) {
                unsigned u23 = cvt_pk_bf16(t1[2], t1[3]);
                T[(unsigned)((18 + tq) * NVOX) + gidx] = (unsigned short)(u23 & 0xffffu);
                T[(unsigned)((19 + tq) * NVOX) + gidx] = (unsigned short)(u23 >> 16);
            } else {
                T[(unsigned)(26 * NVOX) + gidx] = (unsigned short)bf_rne(t1[2]);
            }
        }
    }
}

// Vectorized cost: thread = 8 consecutive w-voxels (aligned; 8 | W). Per
// (kd,kh): 3 aligned uint4 loads (8 bf16 taps) + 2 predicated scalar edge
// loads; kw handled by register shifts.
__global__ __launch_bounds__(256) void cost_kernel(const unsigned short* __restrict__ T,
                                                   float* __restrict__ cost) {
    int t = blockIdx.x * 256 + threadIdx.x;    // over NVOX/8
    int v0 = t * 8;
    int w0 = v0 % W_;
    int h = (v0 / W_) % H_;
    int d = (v0 / HW_) % D_;
    int b = v0 / PLANE;
    float acc[8];
#pragma unroll
    for (int i = 0; i < 8; ++i) acc[i] = 0.f;

#pragma unroll
    for (int kd = 0; kd < 3; ++kd) {
        int dd = d + kd - 1;
        if (dd < 0 || dd >= D_) continue;
#pragma unroll
        for (int kh = 0; kh < 3; ++kh) {
            int hh = h + kh - 1;
            if (hh < 0 || hh >= H_) continue;
            unsigned r = (unsigned)(b * PLANE + dd * HW_ + hh * W_);
            int j = kd * 9 + kh * 3;
            const unsigned short* p0 = T + (size_t)j * NVOX + r;
            const unsigned short* p1 = p0 + NVOX;
            const unsigned short* p2 = p1 + NVOX;
            uint4 A0 = *(const uint4*)(p0 + w0);
            uint4 A1 = *(const uint4*)(p1 + w0);
            uint4 A2 = *(const uint4*)(p2 + w0);
            float eL = (w0 > 0) ? bflo((unsigned)p0[w0 - 1]) : 0.f;
            float eR = (w0 + 8 < W_) ? bflo((unsigned)p2[w0 + 8]) : 0.f;
            unsigned x0[4] = {A0.x, A0.y, A0.z, A0.w};
            unsigned x1[4] = {A1.x, A1.y, A1.z, A1.w};
            unsigned x2[4] = {A2.x, A2.y, A2.z, A2.w};
            float a0[8], a1[8], a2[8];
#pragma unroll
            for (int k = 0; k < 4; ++k) {
                a0[2 * k] = bflo(x0[k]); a0[2 * k + 1] = bfhi(x0[k]);
                a1[2 * k] = bflo(x1[k]); a1[2 * k + 1] = bfhi(x1[k]);
                a2[2 * k] = bflo(x2[k]); a2[2 * k + 1] = bfhi(x2[k]);
            }
            acc[0] += eL + a1[0] + a2[1];
#pragma unroll
            for (int i = 1; i < 7; ++i) acc[i] += a0[i - 1] + a1[i] + a2[i + 1];
            acc[7] += a0[6] + a1[7] + eR;
        }
    }
    float4* cp = (float4*)(cost + v0);
    cp[0] = make_float4(acc[0], acc[1], acc[2], acc[3]);
    cp[1] = make_float4(acc[4], acc[5], acc[6], acc[7]);
}

// Parallel softmax/depth/conf/itg: block = 64 pixels x 4 depth-quarters.
__global__ __launch_bounds__(256) void out_kernel(const float* __restrict__ cost,
                                                  const float* __restrict__ dv,
                                                  float* __restrict__ out) {
    __shared__ float red[4][64];
    const int tid = threadIdx.x;
    const int lane = tid & 63;
    const int wq = tid >> 6;                  // depth quarter
    const int pixg = blockIdx.x * 64 + lane;  // over B*HW
    const int b = pixg / HW_;
    const int pix = pixg - b * HW_;
    const float* cb = cost + (size_t)b * PLANE + pix;

    float p[12];
    float mx = -1e30f;
#pragma unroll
    for (int i = 0; i < 12; ++i) {
        p[i] = cb[(size_t)(wq * 12 + i) * HW_];
        mx = fmaxf(mx, p[i]);
    }
    red[wq][lane] = mx;
    __syncthreads();
    mx = fmaxf(fmaxf(red[0][lane], red[1][lane]), fmaxf(red[2][lane], red[3][lane]));
    float S = 0.f;
#pragma unroll
    for (int i = 0; i < 12; ++i) {
        p[i] = expf(p[i] - mx);
        S += p[i];
    }
    __syncthreads();
    red[wq][lane] = S;
    __syncthreads();
    S = red[0][lane] + red[1][lane] + red[2][lane] + red[3][lane];
    float invS = 1.f / S;
    float S2p = 0.f;
#pragma unroll
    for (int i = 0; i < 12; ++i) {
        p[i] *= invS;             // prob
        S2p += p[i];
    }
    __syncthreads();
    red[wq][lane] = S2p;
    __syncthreads();
    float S2 = red[0][lane] + red[1][lane] + red[2][lane] + red[3][lane];
    float invS2 = 1.f / fmaxf(S2, 1e-12f);
    float dp = 0.f, difp = 0.f;
#pragma unroll
    for (int i = 0; i < 12; ++i) {
        int d0 = wq * 12 + i;
        dp = fmaf(p[i] * invS2, dv[b * D_ + d0], dp);
        difp = fmaf(p[i], (float)d0, difp);
    }
    __syncthreads();
    red[wq][lane] = dp;
    __syncthreads();
    float depth = red[0][lane] + red[1][lane] + red[2][lane] + red[3][lane];
    __syncthreads();
    red[wq][lane] = difp;
    __syncthreads();
    float dif = red[0][lane] + red[1][lane] + red[2][lane] + red[3][lane];
    int di = (int)dif;
    di = min(max(di, 0), D_ - 1);
    float cf = 0.f;
#pragma unroll
    for (int i = 0; i < 12; ++i) {
        int d0 = wq * 12 + i;
        if (d0 >= di - 1 && d0 <= di + 2) cf += p[i];
    }
    __syncthreads();
    red[wq][lane] = cf;
    __syncthreads();
    float conf = red[0][lane] + red[1][lane] + red[2][lane] + red[3][lane];

    if (wq == 0) {
        out[pixg] = depth;
        out[B_ * HW_ + pixg] = conf;
    }
    float* itg = out + 2 * B_ * HW_ + (size_t)b * PLANE + pix;
#pragma unroll
    for (int i = 0; i < 12; ++i)
        itg[(size_t)(wq * 12 + i) * HW_] = p[i] * invS2;
}

extern "C" void kernel_launch(void* const* d_in, const int* in_sizes, int n_in,
                              void* d_out, int out_size, void* d_ws, size_t ws_size,
                              hipStream_t stream) {
    const float* feat = (const float*)d_in[0];   // (B,V,C,H,W)
    const float* proj = (const float*)d_in[1];   // (B,V,2,4,4)
    const float* dv   = (const float*)d_in[2];   // (B,D)
    const float* wreg = (const float*)d_in[3];   // (1,C,3,3,3)
    float* out = (float*)d_out;
    float* ws = (float*)d_ws;

    // workspace layout (floats)
    const size_t rt_off = 0;
    const size_t rt_sz = 128;
    const size_t wtb_off = rt_off + rt_sz;
    const size_t wtb_sz = 512;                            // 2*64*4 uints
    const size_t fcl_off = wtb_off + wtb_sz;
    const size_t fcl_sz = (size_t)B_ * V_ * HW_ * 16;     // fp16 pixels: 16 uints each
    const size_t T_off = fcl_off + fcl_sz;
    const size_t T_sz = (size_t)27 * NVOX / 2;            // bf16 taps (float-slots)
    const size_t cost_off = T_off + T_sz;
    const size_t cost_sz = (size_t)NVOX;
    const size_t need = (cost_off + cost_sz) * sizeof(float);
    if (ws_size < need) return;  // workspace too small — fail loudly

    float* rt = ws + rt_off;
    unsigned* wtb = (unsigned*)(ws + wtb_off);
    unsigned* feat_cl = (unsigned*)(ws + fcl_off);
    unsigned short* T = (unsigned short*)(ws + T_off);
    float* cost = ws + cost_off;

    setup_kernel<<<1, 128, 0, stream>>>(proj, wreg, rt, wtb);
    transpose_kernel<<<(B_ * V_ * HW_) / 256, 256, 0, stream>>>(feat, feat_cl);
    dim3 wgrid(HW_ / 64, D_ / 2, B_);
    warp_kernel<<<wgrid, 256, 0, stream>>>((const unsigned char*)feat_cl, rt, dv, wtb, T);
    cost_kernel<<<(NVOX / 8) / 256, 256, 0, stream>>>(T, cost);
    out_kernel<<<(B_ * HW_) / 64, 256, 0, stream>>>(cost, dv, out);
}

// Round 11
// 191.394 us; speedup vs baseline: 1.8348x; 1.0175x over previous
//
#include <hip/hip_runtime.h>
#include <math.h>

// Problem constants (from setup_inputs): B,V,C,D,H,W = 2,5,32,48,128,160
constexpr int B_ = 2;
constexpr int V_ = 5;
constexpr int C_ = 32;
constexpr int D_ = 48;
constexpr int H_ = 128;
constexpr int W_ = 160;
constexpr int HW_ = H_ * W_;               // 20480
constexpr int NVOX = B_ * D_ * HW_;        // 1,966,080
constexpr int PLANE = D_ * HW_;            // 983,040 (per-batch voxels)

typedef _Float16 half2_t __attribute__((ext_vector_type(2)));
typedef _Float16 half8_t __attribute__((ext_vector_type(8)));
typedef float floatx4 __attribute__((ext_vector_type(4)));

// v_perm selector: result = (a.h1 in low, b.h0 in high) — the "shift by one
// f16 element" stitcher. (indices 4-7 = first operand, 0-3 = second.)
constexpr unsigned SEL_SHIFT = 0x01000706u;

// ---------------- small matrix helpers (device) ----------------

__device__ inline void combine4(const float* pm, float out[4][4]) {
    const float* E = pm;
    const float* K = pm + 16;
    for (int i = 0; i < 3; ++i)
        for (int j = 0; j < 4; ++j) {
            float a = 0.f;
            for (int k = 0; k < 3; ++k) a += K[i * 4 + k] * E[k * 4 + j];
            out[i][j] = a;
        }
    for (int j = 0; j < 4; ++j) out[3][j] = E[12 + j];
}

__device__ inline void invert4(const float A[4][4], float inv[4][4]) {
    float M[4][8];
    for (int i = 0; i < 4; ++i)
        for (int j = 0; j < 4; ++j) {
            M[i][j] = A[i][j];
            M[i][4 + j] = (i == j) ? 1.f : 0.f;
        }
    for (int col = 0; col < 4; ++col) {
        int piv = col;
        float best = fabsf(M[col][col]);
        for (int r = col + 1; r < 4; ++r) {
            float v = fabsf(M[r][col]);
            if (v > best) { best = v; piv = r; }
        }
        if (piv != col)
            for (int j = 0; j < 8; ++j) { float t = M[col][j]; M[col][j] = M[piv][j]; M[piv][j] = t; }
        float ip = 1.f / M[col][col];
        for (int j = 0; j < 8; ++j) M[col][j] *= ip;
        for (int r = 0; r < 4; ++r) {
            if (r == col) continue;
            float f = M[r][col];
            for (int j = 0; j < 8; ++j) M[r][j] -= f * M[col][j];
        }
    }
    for (int i = 0; i < 4; ++i)
        for (int j = 0; j < 4; ++j) inv[i][j] = M[i][4 + j];
}

__device__ inline unsigned h2pack(float a, float b) {   // fp16 RNE pair
    unsigned lo = (unsigned)__builtin_bit_cast(unsigned short, (_Float16)a);
    unsigned hi = (unsigned)__builtin_bit_cast(unsigned short, (_Float16)b);
    return lo | (hi << 16);
}

// setup: (a) per b,v: P = src_proj @ inv(ref_proj) -> rt[12 floats]
//        (b) prepack conv weights as fp16 MFMA A-fragments:
//            A[m=tap=lane&15 (+16i)][k=ch=(lane>>4)*8+j], taps>=27 zero-padded
__global__ void setup_kernel(const float* __restrict__ proj, const float* __restrict__ wreg,
                             float* __restrict__ rt, unsigned* __restrict__ wtb) {
    int t = threadIdx.x;
    if (t < B_) {
        int b = t;
        float ref[4][4], inv[4][4];
        combine4(proj + (size_t)((b * V_ + 0) * 2) * 16, ref);
        invert4(ref, inv);
        for (int v = 1; v < V_; ++v) {
            float src[4][4];
            combine4(proj + (size_t)((b * V_ + v) * 2) * 16, src);
            float P[3][4];
            for (int i = 0; i < 3; ++i)
                for (int j = 0; j < 4; ++j) {
                    float a = 0.f;
                    for (int k = 0; k < 4; ++k) a += src[i][k] * inv[k][j];
                    P[i][j] = a;
                }
            float* o = rt + (size_t)(b * (V_ - 1) + (v - 1)) * 12;
            o[0] = P[0][0]; o[1] = P[0][1]; o[2] = P[0][2];
            o[3] = P[1][0]; o[4] = P[1][1]; o[5] = P[1][2];
            o[6] = P[2][0]; o[7] = P[2][1]; o[8] = P[2][2];
            o[9] = P[0][3]; o[10] = P[1][3]; o[11] = P[2][3];
        }
    }
    if (t < 128) {
        int i = t >> 6;          // which mfma (taps 0-15 / 16-31)
        int lane = t & 63;
        int q = lane >> 4;
        int l = lane & 15;
        int tap = i * 16 + l;
        unsigned u[4];
#pragma unroll
        for (int jj = 0; jj < 4; ++jj) {
            int ch0 = q * 8 + 2 * jj;
            float v0 = (tap < 27) ? wreg[ch0 * 27 + tap] : 0.f;
            float v1 = (tap < 27) ? wreg[(ch0 + 1) * 27 + tap] : 0.f;
            u[jj] = h2pack(v0, v1);
        }
        uint4* o = (uint4*)wtb;
        o[i * 64 + lane] = make_uint4(u[0], u[1], u[2], u[3]);
    }
}

// transpose features (B,V,C,H,W) f32 -> channel-last fp16 (B,V,H,W,C): 64 B/pixel
__global__ __launch_bounds__(256) void transpose_kernel(const float* __restrict__ feat,
                                                        unsigned* __restrict__ feat_cl) {
    int idx = blockIdx.x * 256 + threadIdx.x;  // over B*V*HW
    if (idx >= B_ * V_ * HW_) return;
    int pix = idx % HW_;
    int bv = idx / HW_;
    const float* src = feat + (size_t)bv * C_ * HW_ + pix;
    unsigned u[16];
#pragma unroll
    for (int j = 0; j < 16; ++j)
        u[j] = h2pack(src[(size_t)(2 * j) * HW_], src[(size_t)(2 * j + 1) * HW_]);
    uint4* dst = (uint4*)(feat_cl + (size_t)idx * 16);
    dst[0] = make_uint4(u[0], u[1], u[2], u[3]);
    dst[1] = make_uint4(u[4], u[5], u[6], u[7]);
    dst[2] = make_uint4(u[8], u[9], u[10], u[11]);
    dst[3] = make_uint4(u[12], u[13], u[14], u[15]);
}

// Fused homography warp + bilinear + variance + conv channel-reduction.
// Block = 256 threads = 64 pixels x 4 channel-quarter lanes; grid (320, D, B).
// r7-verified structure (98.8 us, VALUBusy 95%): per-thread computation of ALL
// 4 views' projections (rt block-uniform -> s_load; no broadcast in the
// address chain), r7 coalesced gather pattern (quad lanes = same corner
// pixel, adjacent quarters — r8 proved load-bearing). Warp duration is
// invariant to VALU/occupancy changes (r7/r9/r10 all ~100 us) — vector-memory
// pipe bound; structure frozen. ONLY change vs r7: taps stored as f16 (not
// bf16) so cost_kernel can consume them with packed-f16 math.
// T layout: [j=0..26][b][d][h][w], ushort (f16).
__global__ __launch_bounds__(256) void warp_kernel(const unsigned char* __restrict__ fb,
                                                   const float* __restrict__ rt,
                                                   const float* __restrict__ dv,
                                                   const unsigned* __restrict__ wtb,
                                                   unsigned short* __restrict__ T) {
    const int tid = threadIdx.x;
    const int lane = tid & 63;
    const int cq = tid & 3;                   // channel quarter
    const unsigned cq16 = (unsigned)cq << 4;
    const int b = blockIdx.z;
    const int d = blockIdx.y;
    const int pixb = blockIdx.x * 64;         // block's first pixel
    const int pix = pixb + (tid >> 2);
    const int w = pix % W_;
    const int h = pix / W_;
    const float wf = (float)w, hf = (float)h;
    const float dep = dv[b * D_ + d];         // uniform -> s_load

    // A-fragments (fp16 conv weights), constant per lane
    const uint4* wp = (const uint4*)wtb;
    uint4 a0u = wp[lane];
    uint4 a1u = wp[64 + lane];

    // all 4 views: projection + duplicated packed bilinear weights + corner
    // byte offsets. rt base is block-uniform -> scalar loads.
    unsigned Wv[4][4];                        // half2 (w,w) per corner
    unsigned O[4][4];                         // byte offsets (incl cq16)
#pragma unroll
    for (int v = 0; v < 4; ++v) {
        const float* m = rt + (b * (V_ - 1) + v) * 12;
        float xp = fmaf(fmaf(m[0], wf, fmaf(m[1], hf, m[2])), dep, m[9]);
        float yp = fmaf(fmaf(m[3], wf, fmaf(m[4], hf, m[5])), dep, m[10]);
        float zp = fmaf(fmaf(m[6], wf, fmaf(m[7], hf, m[8])), dep, m[11]);
        float iz = __builtin_amdgcn_rcpf(zp);
        float ix = xp * iz, iy = yp * iz;
        float x0f = floorf(ix), y0f = floorf(iy);
        float wx1 = ix - x0f, wx0 = 1.f - wx1;
        float wy1 = iy - y0f, wy0 = 1.f - wy1;
        float x1f = x0f + 1.f, y1f = y0f + 1.f;
        float wx0v = (x0f >= 0.f && x0f <= (float)(W_ - 1)) ? wx0 : 0.f;
        float wx1v = (x1f >= 0.f && x1f <= (float)(W_ - 1)) ? wx1 : 0.f;
        float wy0v = (y0f >= 0.f && y0f <= (float)(H_ - 1)) ? wy0 : 0.f;
        float wy1v = (y1f >= 0.f && y1f <= (float)(H_ - 1)) ? wy1 : 0.f;
        int x0i = (int)fminf(fmaxf(x0f, 0.f), (float)(W_ - 1));
        int x1i = (int)fminf(fmaxf(x1f, 0.f), (float)(W_ - 1));
        int y0i = (int)fminf(fmaxf(y0f, 0.f), (float)(H_ - 1));
        int y1i = (int)fminf(fmaxf(y1f, 0.f), (float)(H_ - 1));
        float w00 = wx0v * wy0v, w01 = wx1v * wy0v;
        float w10 = wx0v * wy1v, w11 = wx1v * wy1v;
        Wv[v][0] = __builtin_bit_cast(unsigned, __builtin_amdgcn_cvt_pkrtz(w00, w00));
        Wv[v][1] = __builtin_bit_cast(unsigned, __builtin_amdgcn_cvt_pkrtz(w01, w01));
        Wv[v][2] = __builtin_bit_cast(unsigned, __builtin_amdgcn_cvt_pkrtz(w10, w10));
        Wv[v][3] = __builtin_bit_cast(unsigned, __builtin_amdgcn_cvt_pkrtz(w11, w11));
        O[v][0] = ((unsigned)(y0i * W_ + x0i) << 6) + cq16;
        O[v][1] = ((unsigned)(y0i * W_ + x1i) << 6) + cq16;
        O[v][2] = ((unsigned)(y1i * W_ + x0i) << 6) + cq16;
        O[v][3] = ((unsigned)(y1i * W_ + x1i) << 6) + cq16;
    }

    // ref view: own pixel, own 8 channels (fp16x8 = one 16B load)
    half2_t s2[4], q2[4];
    {
        const unsigned char* rb = fb + (size_t)(b * V_) * HW_ * 64;
        uint4 r = *(const uint4*)(rb + (((unsigned)pix) << 6) + cq16);
        unsigned ru[4] = {r.x, r.y, r.z, r.w};
#pragma unroll
        for (int jj = 0; jj < 4; ++jj) {
            half2_t f = __builtin_bit_cast(half2_t, ru[jj]);
            s2[jj] = f;
            q2[jj] = f * f;
        }
    }

    // gathers + combine per view (addresses are pure VALU, ready upfront)
#pragma unroll
    for (int v = 0; v < 4; ++v) {
        const unsigned char* base = fb + (size_t)(b * V_ + v + 1) * HW_ * 64;
        uint4 c0 = *(const uint4*)(base + O[v][0]);
        uint4 c1 = *(const uint4*)(base + O[v][1]);
        uint4 c2 = *(const uint4*)(base + O[v][2]);
        uint4 c3 = *(const uint4*)(base + O[v][3]);
        half2_t Wa = __builtin_bit_cast(half2_t, Wv[v][0]);
        half2_t Wb = __builtin_bit_cast(half2_t, Wv[v][1]);
        half2_t Wc = __builtin_bit_cast(half2_t, Wv[v][2]);
        half2_t Wd = __builtin_bit_cast(half2_t, Wv[v][3]);
        unsigned u0[4] = {c0.x, c0.y, c0.z, c0.w};
        unsigned u1[4] = {c1.x, c1.y, c1.z, c1.w};
        unsigned u2[4] = {c2.x, c2.y, c2.z, c2.w};
        unsigned u3[4] = {c3.x, c3.y, c3.z, c3.w};
#pragma unroll
        for (int jj = 0; jj < 4; ++jj) {
            half2_t acc = __builtin_bit_cast(half2_t, u0[jj]) * Wa
                        + __builtin_bit_cast(half2_t, u1[jj]) * Wb
                        + __builtin_bit_cast(half2_t, u2[jj]) * Wc
                        + __builtin_bit_cast(half2_t, u3[jj]) * Wd;
            s2[jj] += acc;                    // v_pk_add_f16
            q2[jj] += acc * acc;              // v_pk_fma_f16
        }
    }

    // variance for this thread's 8 channels, fully packed f16
    const _Float16 ivh = (_Float16)(1.0f / (float)V_);
    const half2_t iv2 = {ivh, ivh};
    unsigned pk[4];
#pragma unroll
    for (int jj = 0; jj < 4; ++jj) {
        half2_t ms = s2[jj] * iv2;
        half2_t var = q2[jj] * iv2 - ms * ms;
        pk[jj] = __builtin_bit_cast(unsigned, var);
    }

    // permute to B-fragment layout: target lane L gets (voxel L&15, quarter L>>4)
    // which lives in source lane (L&15)*4 + (L>>4)
    uint4 bu;
    {
        int srcl = ((lane & 15) << 2) + (lane >> 4);
        bu.x = (unsigned)__shfl((int)pk[0], srcl);
        bu.y = (unsigned)__shfl((int)pk[1], srcl);
        bu.z = (unsigned)__shfl((int)pk[2], srcl);
        bu.w = (unsigned)__shfl((int)pk[3], srcl);
    }
    half8_t bfrag = __builtin_bit_cast(half8_t, bu);
    half8_t afrag0 = __builtin_bit_cast(half8_t, a0u);
    half8_t afrag1 = __builtin_bit_cast(half8_t, a1u);

    floatx4 z = {0.f, 0.f, 0.f, 0.f};
    // D[m=tap][n=voxel-in-wave]; lane L: col=L&15, rows=(L>>4)*4+r
    floatx4 t0 = __builtin_amdgcn_mfma_f32_16x16x32_f16(afrag0, bfrag, z, 0, 0, 0);
    floatx4 t1 = __builtin_amdgcn_mfma_f32_16x16x32_f16(afrag1, bfrag, z, 0, 0, 0);

    // store taps as f16 straight to the 27 T planes (pk-convert pairs, lo/hi stores)
    const unsigned gidx = (unsigned)(b * PLANE + d * HW_ + pixb + ((tid >> 6) << 4) + (lane & 15));
    const int tq = (lane >> 4) << 2;
    {
        unsigned u01 = __builtin_bit_cast(unsigned, __builtin_amdgcn_cvt_pkrtz(t0[0], t0[1]));
        unsigned u23 = __builtin_bit_cast(unsigned, __builtin_amdgcn_cvt_pkrtz(t0[2], t0[3]));
        T[(unsigned)((tq + 0) * NVOX) + gidx] = (unsigned short)(u01 & 0xffffu);
        T[(unsigned)((tq + 1) * NVOX) + gidx] = (unsigned short)(u01 >> 16);
        T[(unsigned)((tq + 2) * NVOX) + gidx] = (unsigned short)(u23 & 0xffffu);
        T[(unsigned)((tq + 3) * NVOX) + gidx] = (unsigned short)(u23 >> 16);
    }
    if (tq < 12) {                            // taps 16+tq .. min(19+tq,26)
        unsigned u01 = __builtin_bit_cast(unsigned, __builtin_amdgcn_cvt_pkrtz(t1[0], t1[1]));
        T[(unsigned)((16 + tq) * NVOX) + gidx] = (unsigned short)(u01 & 0xffffu);
        T[(unsigned)((17 + tq) * NVOX) + gidx] = (unsigned short)(u01 >> 16);
        if (tq < 8) {
            unsigned u23 = __builtin_bit_cast(unsigned, __builtin_amdgcn_cvt_pkrtz(t1[2], t1[3]));
            T[(unsigned)((18 + tq) * NVOX) + gidx] = (unsigned short)(u23 & 0xffffu);
            T[(unsigned)((19 + tq) * NVOX) + gidx] = (unsigned short)(u23 >> 16);
        } else {
            unsigned u2 = __builtin_bit_cast(unsigned, __builtin_amdgcn_cvt_pkrtz(t1[2], t1[2]));
            T[(unsigned)(26 * NVOX) + gidx] = (unsigned short)(u2 & 0xffffu);
        }
    }
}

// Vectorized cost: thread = 8 consecutive w-voxels (aligned; 8 | W). Taps are
// f16: per (kd,kh) the mid plane accumulates with 4 v_pk_add_f16; the +-1-w
// shifted planes are stitched with one v_perm per dword (SEL_SHIFT builds
// (hi(prev), lo(cur))) then pk_add — 21 VALU ops vs 48 in the f32-unpack
// version. Accumulate packed f16, convert to f32 once at the end.
__global__ __launch_bounds__(256) void cost_kernel(const unsigned short* __restrict__ T,
                                                   float* __restrict__ cost) {
    int t = blockIdx.x * 256 + threadIdx.x;    // over NVOX/8
    int v0 = t * 8;
    int w0 = v0 % W_;
    int h = (v0 / W_) % H_;
    int d = (v0 / HW_) % D_;
    int b = v0 / PLANE;
    half2_t acc[4];
#pragma unroll
    for (int k = 0; k < 4; ++k) acc[k] = (half2_t){(_Float16)0.f, (_Float16)0.f};

#pragma unroll
    for (int kd = 0; kd < 3; ++kd) {
        int dd = d + kd - 1;
        if (dd < 0 || dd >= D_) continue;
#pragma unroll
        for (int kh = 0; kh < 3; ++kh) {
            int hh = h + kh - 1;
            if (hh < 0 || hh >= H_) continue;
            unsigned r = (unsigned)(b * PLANE + dd * HW_ + hh * W_);
            int j = kd * 9 + kh * 3;
            const unsigned short* p0 = T + (size_t)j * NVOX + r;
            const unsigned short* p1 = p0 + NVOX;
            const unsigned short* p2 = p1 + NVOX;
            uint4 A0 = *(const uint4*)(p0 + w0);
            uint4 A1 = *(const uint4*)(p1 + w0);
            uint4 A2 = *(const uint4*)(p2 + w0);
            unsigned eL = (w0 > 0) ? (unsigned)p0[w0 - 1] : 0u;       // f16 bits
            unsigned eR = (w0 + 8 < W_) ? (unsigned)p2[w0 + 8] : 0u;  // f16 bits
            unsigned x0[4] = {A0.x, A0.y, A0.z, A0.w};
            unsigned x1[4] = {A1.x, A1.y, A1.z, A1.w};
            unsigned x2[4] = {A2.x, A2.y, A2.z, A2.w};
            // mid plane (kw=1): acc[2k,2k+1] += a1[2k,2k+1]
#pragma unroll
            for (int k = 0; k < 4; ++k)
                acc[k] += __builtin_bit_cast(half2_t, x1[k]);
            // left plane (kw=0) shifted -1: acc[2k,2k+1] += (a0[2k-1], a0[2k])
            unsigned prev = eL << 16;          // a0[-1] sits in hi half
#pragma unroll
            for (int k = 0; k < 4; ++k) {
                unsigned Lk = __builtin_amdgcn_perm(k ? x0[k - 1] : prev, x0[k], SEL_SHIFT);
                acc[k] += __builtin_bit_cast(half2_t, Lk);
            }
            // right plane (kw=2) shifted +1: acc[2k,2k+1] += (a2[2k+1], a2[2k+2])
#pragma unroll
            for (int k = 0; k < 4; ++k) {
                unsigned nxt = (k < 3) ? x2[k + 1] : eR;  // a2[8] = eR in lo half
                unsigned Rk = __builtin_amdgcn_perm(x2[k], nxt, SEL_SHIFT);
                acc[k] += __builtin_bit_cast(half2_t, Rk);
            }
        }
    }
    float4* cp = (float4*)(cost + v0);
    cp[0] = make_float4((float)acc[0][0], (float)acc[0][1], (float)acc[1][0], (float)acc[1][1]);
    cp[1] = make_float4((float)acc[2][0], (float)acc[2][1], (float)acc[3][0], (float)acc[3][1]);
}

// Parallel softmax/depth/conf/itg: block = 64 pixels x 4 depth-quarters.
__global__ __launch_bounds__(256) void out_kernel(const float* __restrict__ cost,
                                                  const float* __restrict__ dv,
                                                  float* __restrict__ out) {
    __shared__ float red[4][64];
    const int tid = threadIdx.x;
    const int lane = tid & 63;
    const int wq = tid >> 6;                  // depth quarter
    const int pixg = blockIdx.x * 64 + lane;  // over B*HW
    const int b = pixg / HW_;
    const int pix = pixg - b * HW_;
    const float* cb = cost + (size_t)b * PLANE + pix;

    float p[12];
    float mx = -1e30f;
#pragma unroll
    for (int i = 0; i < 12; ++i) {
        p[i] = cb[(size_t)(wq * 12 + i) * HW_];
        mx = fmaxf(mx, p[i]);
    }
    red[wq][lane] = mx;
    __syncthreads();
    mx = fmaxf(fmaxf(red[0][lane], red[1][lane]), fmaxf(red[2][lane], red[3][lane]));
    float S = 0.f;
#pragma unroll
    for (int i = 0; i < 12; ++i) {
        p[i] = expf(p[i] - mx);
        S += p[i];
    }
    __syncthreads();
    red[wq][lane] = S;
    __syncthreads();
    S = red[0][lane] + red[1][lane] + red[2][lane] + red[3][lane];
    float invS = 1.f / S;
    float S2p = 0.f;
#pragma unroll
    for (int i = 0; i < 12; ++i) {
        p[i] *= invS;             // prob
        S2p += p[i];
    }
    __syncthreads();
    red[wq][lane] = S2p;
    __syncthreads();
    float S2 = red[0][lane] + red[1][lane] + red[2][lane] + red[3][lane];
    float invS2 = 1.f / fmaxf(S2, 1e-12f);
    float dp = 0.f, difp = 0.f;
#pragma unroll
    for (int i = 0; i < 12; ++i) {
        int d0 = wq * 12 + i;
        dp = fmaf(p[i] * invS2, dv[b * D_ + d0], dp);
        difp = fmaf(p[i], (float)d0, difp);
    }
    __syncthreads();
    red[wq][lane] = dp;
    __syncthreads();
    float depth = red[0][lane] + red[1][lane] + red[2][lane] + red[3][lane];
    __syncthreads();
    red[wq][lane] = difp;
    __syncthreads();
    float dif = red[0][lane] + red[1][lane] + red[2][lane] + red[3][lane];
    int di = (int)dif;
    di = min(max(di, 0), D_ - 1);
    float cf = 0.f;
#pragma unroll
    for (int i = 0; i < 12; ++i) {
        int d0 = wq * 12 + i;
        if (d0 >= di - 1 && d0 <= di + 2) cf += p[i];
    }
    __syncthreads();
    red[wq][lane] = cf;
    __syncthreads();
    float conf = red[0][lane] + red[1][lane] + red[2][lane] + red[3][lane];

    if (wq == 0) {
        out[pixg] = depth;
        out[B_ * HW_ + pixg] = conf;
    }
    float* itg = out + 2 * B_ * HW_ + (size_t)b * PLANE + pix;
#pragma unroll
    for (int i = 0; i < 12; ++i)
        itg[(size_t)(wq * 12 + i) * HW_] = p[i] * invS2;
}

extern "C" void kernel_launch(void* const* d_in, const int* in_sizes, int n_in,
                              void* d_out, int out_size, void* d_ws, size_t ws_size,
                              hipStream_t stream) {
    const float* feat = (const float*)d_in[0];   // (B,V,C,H,W)
    const float* proj = (const float*)d_in[1];   // (B,V,2,4,4)
    const float* dv   = (const float*)d_in[2];   // (B,D)
    const float* wreg = (const float*)d_in[3];   // (1,C,3,3,3)
    float* out = (float*)d_out;
    float* ws = (float*)d_ws;

    // workspace layout (floats)
    const size_t rt_off = 0;
    const size_t rt_sz = 128;
    const size_t wtb_off = rt_off + rt_sz;
    const size_t wtb_sz = 512;                            // 2*64*4 uints
    const size_t fcl_off = wtb_off + wtb_sz;
    const size_t fcl_sz = (size_t)B_ * V_ * HW_ * 16;     // fp16 pixels: 16 uints each
    const size_t T_off = fcl_off + fcl_sz;
    const size_t T_sz = (size_t)27 * NVOX / 2;            // f16 taps (float-slots)
    const size_t cost_off = T_off + T_sz;
    const size_t cost_sz = (size_t)NVOX;
    const size_t need = (cost_off + cost_sz) * sizeof(float);
    if (ws_size < need) return;  // workspace too small — fail loudly

    float* rt = ws + rt_off;
    unsigned* wtb = (unsigned*)(ws + wtb_off);
    unsigned* feat_cl = (unsigned*)(ws + fcl_off);
    unsigned short* T = (unsigned short*)(ws + T_off);
    float* cost = ws + cost_off;

    setup_kernel<<<1, 128, 0, stream>>>(proj, wreg, rt, wtb);
    transpose_kernel<<<(B_ * V_ * HW_) / 256, 256, 0, stream>>>(feat, feat_cl);
    dim3 wgrid(HW_ / 64, D_, B_);
    warp_kernel<<<wgrid, 256, 0, stream>>>((const unsigned char*)feat_cl, rt, dv, wtb, T);
    cost_kernel<<<(NVOX / 8) / 256, 256, 0, stream>>>(T, cost);
    out_kernel<<<(B_ * HW_) / 64, 256, 0, stream>>>(cost, dv, out);
}